// Round 1
// baseline (2716.225 us; speedup 1.0000x reference)
//
#include <hip/hip_runtime.h>
#include <cstdint>
#include <cstddef>

// ---------------- problem constants ----------------
#define P_TOT    16384      // B*H*W = 4*64*64
#define CIN      1024
#define CMID     512
#define NA       9
#define NANC     147456     // P_TOT * NA
#define PRE_NMS  6000
#define POST_NMS 300
#define IOU_THR  0.7f

// output layout (floats): cls_pred | reg_pred | proposals
#define CLS_OFF  0
#define REG_OFF  147456
#define PROP_OFF 737280

// ---------------- workspace layout (bytes) ----------------
#define WS_H        0u          // 16384*512*4   = 33554432
#define WS_LOGITS   33554432u   // 16384*48*4    = 3145728
#define WS_BOXES    36700160u   // 147456*4*4    = 2359296
#define WS_HIST     39059456u   // 65536*4       = 262144
#define WS_META     39321600u   // 64*4          = 256   (meta[0]=cnt, meta[1]=T)
#define WS_COLL     39321856u   // 8192*8        = 65536
#define WS_SBOX     39387392u   // 6000*16       = 96000
#define CAP_COLL    8192

__device__ __forceinline__ int imin(int a, int b) { return a < b ? a : b; }

// =====================================================================
// GEMM1: h[16384x512] = relu(feats[16384x1024] @ w_bneck[1024x512] + b)
// fp32 vector GEMM, 128x128 tile, BK=16, 256 threads, 8x8 microtile.
// fp32 (not bf16 MFMA) is REQUIRED: NMS ordering is sensitive to ~1e-5
// score noise; bf16 would reorder proposals.
// =====================================================================
__global__ __launch_bounds__(256, 2) void gemm1_kernel(
    const float* __restrict__ A, const float* __restrict__ Bw,
    const float* __restrict__ bias, float* __restrict__ C)
{
    __shared__ float As[16][132];   // transposed A tile [k][m], padded
    __shared__ float Bs[16][128];   // B tile [k][n]

    const int t  = threadIdx.x;
    const int m0 = blockIdx.x * 128;
    const int n0 = blockIdx.y * 128;
    const int tx = t & 15;          // n-dir
    const int ty = t >> 4;          // m-dir (0..15)

    // global-load index mapping
    const int ar0 = t >> 2;               // A row within tile (0..63), second at +64
    const int ac0 = (t & 3) * 4;          // A col within tile (k)
    const int br0 = t >> 5;               // B row within tile (0..7), second at +8
    const int bc0 = (t & 31) * 4;         // B col within tile

    float acc[8][8];
#pragma unroll
    for (int r = 0; r < 8; ++r)
#pragma unroll
        for (int c = 0; c < 8; ++c) acc[r][c] = 0.f;

    float4 pa0, pa1, pb0, pb1;
    auto loadTiles = [&](int k0) {
        pa0 = *(const float4*)(A + (size_t)(m0 + ar0) * CIN + k0 + ac0);
        pa1 = *(const float4*)(A + (size_t)(m0 + ar0 + 64) * CIN + k0 + ac0);
        pb0 = *(const float4*)(Bw + (size_t)(k0 + br0) * CMID + n0 + bc0);
        pb1 = *(const float4*)(Bw + (size_t)(k0 + br0 + 8) * CMID + n0 + bc0);
    };
    auto storeTiles = [&]() {
        As[ac0 + 0][ar0] = pa0.x; As[ac0 + 1][ar0] = pa0.y;
        As[ac0 + 2][ar0] = pa0.z; As[ac0 + 3][ar0] = pa0.w;
        As[ac0 + 0][ar0 + 64] = pa1.x; As[ac0 + 1][ar0 + 64] = pa1.y;
        As[ac0 + 2][ar0 + 64] = pa1.z; As[ac0 + 3][ar0 + 64] = pa1.w;
        *(float4*)&Bs[br0][bc0]     = pb0;
        *(float4*)&Bs[br0 + 8][bc0] = pb1;
    };

    loadTiles(0);
    storeTiles();
    __syncthreads();

    for (int kt = 0; kt < 64; ++kt) {
        if (kt < 63) loadTiles((kt + 1) * 16);   // prefetch next tile (overlaps compute)
#pragma unroll
        for (int kk = 0; kk < 16; ++kk) {
            float4 a0 = *(const float4*)&As[kk][ty * 4];
            float4 a1 = *(const float4*)&As[kk][64 + ty * 4];
            float4 b0 = *(const float4*)&Bs[kk][tx * 4];
            float4 b1 = *(const float4*)&Bs[kk][64 + tx * 4];
            float av[8] = {a0.x, a0.y, a0.z, a0.w, a1.x, a1.y, a1.z, a1.w};
            float bv[8] = {b0.x, b0.y, b0.z, b0.w, b1.x, b1.y, b1.z, b1.w};
#pragma unroll
            for (int r = 0; r < 8; ++r)
#pragma unroll
                for (int c = 0; c < 8; ++c) acc[r][c] += av[r] * bv[c];
        }
        __syncthreads();
        if (kt < 63) { storeTiles(); __syncthreads(); }
    }

    float4 bias0 = *(const float4*)(bias + n0 + tx * 4);
    float4 bias1 = *(const float4*)(bias + n0 + 64 + tx * 4);
    float bv0[4] = {bias0.x, bias0.y, bias0.z, bias0.w};
    float bv1[4] = {bias1.x, bias1.y, bias1.z, bias1.w};
#pragma unroll
    for (int r = 0; r < 8; ++r) {
        int mrow = m0 + ((r < 4) ? (ty * 4 + r) : (64 + ty * 4 + (r - 4)));
        float4 o0, o1;
        o0.x = fmaxf(acc[r][0] + bv0[0], 0.f);
        o0.y = fmaxf(acc[r][1] + bv0[1], 0.f);
        o0.z = fmaxf(acc[r][2] + bv0[2], 0.f);
        o0.w = fmaxf(acc[r][3] + bv0[3], 0.f);
        o1.x = fmaxf(acc[r][4] + bv1[0], 0.f);
        o1.y = fmaxf(acc[r][5] + bv1[1], 0.f);
        o1.z = fmaxf(acc[r][6] + bv1[2], 0.f);
        o1.w = fmaxf(acc[r][7] + bv1[3], 0.f);
        *(float4*)(C + (size_t)mrow * CMID + n0 + tx * 4)      = o0;
        *(float4*)(C + (size_t)mrow * CMID + n0 + 64 + tx * 4) = o1;
    }
}

// =====================================================================
// GEMM2: logits[16384 x 48(45 used)] = h[16384x512] @ [w_cls | w_reg]
// 64 pixels x 48 outs per block, BK=32. Raw logits (bias added, no act).
// =====================================================================
__global__ __launch_bounds__(256) void gemm2_kernel(
    const float* __restrict__ h,
    const float* __restrict__ wcls, const float* __restrict__ bcls,
    const float* __restrict__ wreg, const float* __restrict__ breg,
    float* __restrict__ logits)
{
    __shared__ float hS[64][37];   // padded to break bank conflicts
    __shared__ float wS[32][48];

    const int t  = threadIdx.x;
    const int p0 = blockIdx.x * 64;
    const int pg = t & 15;         // pixel group: pixels pg*4 .. pg*4+3
    const int og = t >> 4;         // out group: outs og*3 .. og*3+2

    float acc[4][3] = {};

    for (int kt = 0; kt < 16; ++kt) {
        int k0 = kt * 32;
        // stage h tile 64x32
#pragma unroll
        for (int i = 0; i < 2; ++i) {
            int idx = t + i * 256;
            int r = idx >> 3, c4 = (idx & 7) * 4;
            float4 v = *(const float4*)(h + (size_t)(p0 + r) * CMID + k0 + c4);
            hS[r][c4 + 0] = v.x; hS[r][c4 + 1] = v.y;
            hS[r][c4 + 2] = v.z; hS[r][c4 + 3] = v.w;
        }
        // stage combined weight tile 32x48 (cols: 0..8 cls, 9..44 reg, 45..47 zero)
#pragma unroll
        for (int i = 0; i < 6; ++i) {
            int idx = t + i * 256;
            int kk = idx / 48, o = idx - kk * 48;
            float val = 0.f;
            if (o < 9)       val = wcls[(size_t)(k0 + kk) * 9 + o];
            else if (o < 45) val = wreg[(size_t)(k0 + kk) * 36 + (o - 9)];
            wS[kk][o] = val;
        }
        __syncthreads();
#pragma unroll 8
        for (int kk = 0; kk < 32; ++kk) {
            float h0 = hS[pg * 4 + 0][kk], h1 = hS[pg * 4 + 1][kk];
            float h2 = hS[pg * 4 + 2][kk], h3 = hS[pg * 4 + 3][kk];
            float w0 = wS[kk][og * 3 + 0], w1 = wS[kk][og * 3 + 1], w2 = wS[kk][og * 3 + 2];
            acc[0][0] += h0 * w0; acc[0][1] += h0 * w1; acc[0][2] += h0 * w2;
            acc[1][0] += h1 * w0; acc[1][1] += h1 * w1; acc[1][2] += h1 * w2;
            acc[2][0] += h2 * w0; acc[2][1] += h2 * w1; acc[2][2] += h2 * w2;
            acc[3][0] += h3 * w0; acc[3][1] += h3 * w1; acc[3][2] += h3 * w2;
        }
        __syncthreads();
    }
#pragma unroll
    for (int c = 0; c < 3; ++c) {
        int o = og * 3 + c;
        if (o < 45) {
            float bv = (o < 9) ? bcls[o] : breg[o - 9];
#pragma unroll
            for (int j = 0; j < 4; ++j)
                logits[(size_t)(p0 + pg * 4 + j) * 48 + o] = acc[j][c] + bv;
        }
    }
}

// =====================================================================
// Decode: sigmoid -> cls_pred out; raw reg -> reg_pred out; box decode
// (clip [0,1]) -> boxes ws; histogram of score upper-16 float bits.
// =====================================================================
__global__ __launch_bounds__(256) void decode_kernel(
    const float* __restrict__ logits, const float4* __restrict__ ancs,
    float* __restrict__ out, float4* __restrict__ boxes,
    unsigned int* __restrict__ hist)
{
    int i = blockIdx.x * 256 + threadIdx.x;     // < 147456
    int p = i / 9, a = i - p * 9;
    const float* lrow = logits + (size_t)p * 48;
    float lg = lrow[a];
    float score = 1.f / (1.f + expf(-lg));
    out[CLS_OFF + i] = score;

    float r0 = lrow[9 + a * 4 + 0];
    float r1 = lrow[9 + a * 4 + 1];
    float r2 = lrow[9 + a * 4 + 2];
    float r3 = lrow[9 + a * 4 + 3];
    float4 rg; rg.x = r0; rg.y = r1; rg.z = r2; rg.w = r3;
    *(float4*)(out + REG_OFF + (size_t)i * 4) = rg;

    float4 an = ancs[i];
    float cx = an.x + r0 * an.z;
    float cy = an.y + r1 * an.w;
    float ww = an.z * expf(r2);
    float hh = an.w * expf(r3);
    float4 bb;
    bb.x = fminf(fmaxf(cx - ww * 0.5f, 0.f), 1.f);
    bb.y = fminf(fmaxf(cy - hh * 0.5f, 0.f), 1.f);
    bb.z = fminf(fmaxf(cx + ww * 0.5f, 0.f), 1.f);
    bb.w = fminf(fmaxf(cy + hh * 0.5f, 0.f), 1.f);
    boxes[i] = bb;

    unsigned int sb = __float_as_uint(score);   // positive -> bit-monotone
    atomicAdd(&hist[sb >> 16], 1u);
}

// =====================================================================
// Scan: find threshold bin T = max bin with cum(>=T) >= PRE_NMS.
// =====================================================================
__global__ __launch_bounds__(256) void scan_kernel(
    const unsigned int* __restrict__ hist, unsigned int* __restrict__ meta)
{
    __shared__ unsigned int sums[256];
    __shared__ unsigned int sc[256];
    __shared__ unsigned int sc2[256];
    __shared__ int cstar;
    __shared__ unsigned int saShared;
    __shared__ int tbin;

    int t = threadIdx.x;
    if (t == 0) tbin = -1;

    // chunk sums (chunk = 256 contiguous bins)
    unsigned int s = 0;
    int base = t << 8;
    for (int b = 0; b < 256; b += 4) {
        uint4 v = *(const uint4*)(hist + base + b);
        s += v.x + v.y + v.z + v.w;
    }
    sums[t] = s;
    __syncthreads();

    // inclusive scan of reversed chunk sums: sc[t] = cum(chunks >= 255-t)
    sc[t] = sums[255 - t];
    __syncthreads();
    for (int off = 1; off < 256; off <<= 1) {
        unsigned int v = sc[t];
        unsigned int add = (t >= off) ? sc[t - off] : 0u;
        __syncthreads();
        sc[t] = v + add;
        __syncthreads();
    }
    {   // find chunk containing the crossing
        unsigned int sa = (t == 255) ? 0u : sc[254 - t];  // strictly-above chunk t
        if (sa < PRE_NMS && sa + sums[t] >= PRE_NMS) { cstar = t; saShared = sa; }
    }
    __syncthreads();

    int c = cstar;
    unsigned int SA = saShared;
    // suffix scan within chunk c
    sc2[t] = hist[c * 256 + 255 - t];
    __syncthreads();
    for (int off = 1; off < 256; off <<= 1) {
        unsigned int v = sc2[t];
        unsigned int add = (t >= off) ? sc2[t - off] : 0u;
        __syncthreads();
        sc2[t] = v + add;
        __syncthreads();
    }
    {
        unsigned int si = sc2[255 - t];            // cum within chunk from bin t up
        int cand = (SA + si >= PRE_NMS) ? t : -1;  // T = max bin with cond
        atomicMax(&tbin, cand);
    }
    __syncthreads();
    if (t == 0) meta[1] = (unsigned int)(c * 256 + tbin);
}

// =====================================================================
// Collect: all anchors with score bin >= T  ->  composite sort keys.
// key = score_bits<<32 | (0xFFFFFFFF - idx): descending sort == stable
// argsort(-score) with index tie-break, matching jnp.argsort semantics.
// =====================================================================
__global__ __launch_bounds__(256) void collect_kernel(
    const float* __restrict__ scores, const unsigned int* __restrict__ meta,
    unsigned long long* __restrict__ coll, unsigned int* __restrict__ cnt)
{
    int i = blockIdx.x * 256 + threadIdx.x;
    unsigned int T = meta[1];
    unsigned int sb = __float_as_uint(scores[i]);
    if ((sb >> 16) >= T) {
        unsigned int pos = atomicAdd(cnt, 1u);
        if (pos < CAP_COLL)
            coll[pos] = ((unsigned long long)sb << 32) |
                        (unsigned long long)(0xFFFFFFFFu - (unsigned int)i);
    }
}

// =====================================================================
// Sort: single-block bitonic sort (descending) of up to 8192 keys in LDS
// (exactly 64KB), then gather top-6000 boxes in sorted order.
// =====================================================================
__global__ __launch_bounds__(1024) void sort_kernel(
    const unsigned long long* __restrict__ coll,
    const unsigned int* __restrict__ cnt,
    const float4* __restrict__ boxes, float4* __restrict__ sboxes)
{
    __shared__ unsigned long long keys[8192];   // 64 KB
    int t = threadIdx.x;
    unsigned int n = cnt[0];
    if (n > CAP_COLL) n = CAP_COLL;
    for (int j = t; j < 8192; j += 1024)
        keys[j] = (j < (int)n) ? coll[j] : 0ULL;
    __syncthreads();

    for (int k = 2; k <= 8192; k <<= 1) {
        for (int j = k >> 1; j > 0; j >>= 1) {
            for (int u = t; u < 4096; u += 1024) {
                int i1 = ((u & ~(j - 1)) << 1) | (u & (j - 1));
                int i2 = i1 | j;
                unsigned long long a = keys[i1], b = keys[i2];
                bool up = (i1 & k) == 0;
                bool sw = up ? (a < b) : (a > b);   // flipped comparator -> descending
                if (sw) { keys[i1] = b; keys[i2] = a; }
            }
            __syncthreads();
        }
    }
    for (int j = t; j < PRE_NMS; j += 1024) {
        unsigned int idx = 0xFFFFFFFFu - (unsigned int)(keys[j] & 0xFFFFFFFFULL);
        if (idx > NANC - 1) idx = NANC - 1;   // safety clamp
        sboxes[j] = boxes[idx];
    }
}

// =====================================================================
// NMS: single block, exact reference semantics. valid bitmask in LDS;
// wave0 finds first set bit (shfl reduce); each wave owns one 64-bit
// word per pass and clears via __ballot (single writer per word).
// Self-suppression via (j == sl). Boxes read from L2 (96KB > LDS budget).
// =====================================================================
__global__ __launch_bounds__(1024) void nms_kernel(
    const float4* __restrict__ sboxes, float* __restrict__ prop)
{
    __shared__ float ar[PRE_NMS];                 // 24 KB
    __shared__ unsigned long long valid[94];
    __shared__ int selIdx;

    int t = threadIdx.x;
    for (int j = t; j < PRE_NMS; j += 1024) {
        float4 b = sboxes[j];
        ar[j] = (b.z - b.x) * (b.w - b.y);
    }
    if (t < 94) valid[t] = (t == 93) ? ((1ULL << 48) - 1ULL) : ~0ULL;
    for (int j = t; j < POST_NMS * 4; j += 1024) prop[j] = 0.f;  // d_out is poisoned
    __syncthreads();

    const int lane = t & 63, wv = t >> 6;
    for (int s = 0; s < POST_NMS; ++s) {
        if (t < 64) {
            int c = 0x7fffffff;
            unsigned long long w1 = valid[t];
            if (w1) c = (t << 6) + __builtin_ctzll(w1);
            if (t < 30) {
                unsigned long long w2 = valid[64 + t];
                if (w2) c = imin(c, ((64 + t) << 6) + __builtin_ctzll(w2));
            }
#pragma unroll
            for (int off = 32; off > 0; off >>= 1)
                c = imin(c, __shfl_down(c, off, 64));
            if (t == 0) selIdx = (c == 0x7fffffff) ? -1 : c;
        }
        __syncthreads();
        int sl = selIdx;
        if (sl < 0) break;   // all remaining rows already zeroed

        float4 sb = sboxes[sl];
        float sa = ar[sl];
#pragma unroll
        for (int it = 0; it < 6; ++it) {
            int wd = wv + it * 16;
            int j = (wd << 6) + lane;
            bool sup = false;
            if (j < PRE_NMS) {
                float4 b = sboxes[j];
                float iw = fmaxf(fminf(sb.z, b.z) - fmaxf(sb.x, b.x), 0.f);
                float ih = fmaxf(fminf(sb.w, b.w) - fmaxf(sb.y, b.y), 0.f);
                float inter = iw * ih;
                float uni = sa + ar[j] - inter;
                float iou = (uni > 0.f) ? (inter / uni) : 0.f;
                sup = (iou > IOU_THR) || (j == sl);
            }
            unsigned long long m = __ballot(sup);
            if (lane == 0 && m) valid[wd] &= ~m;
        }
        if (t == 0) {
            prop[s * 4 + 0] = sb.x; prop[s * 4 + 1] = sb.y;
            prop[s * 4 + 2] = sb.z; prop[s * 4 + 3] = sb.w;
        }
        __syncthreads();
    }
}

// =====================================================================
extern "C" void kernel_launch(void* const* d_in, const int* in_sizes, int n_in,
                              void* d_out, int out_size, void* d_ws, size_t ws_size,
                              hipStream_t stream)
{
    const float*  feats   = (const float*)d_in[0];
    const float4* ancs    = (const float4*)d_in[1];
    // d_in[2] = ancs_valid (unused by reference)
    const float*  w_bneck = (const float*)d_in[3];
    const float*  b_bneck = (const float*)d_in[4];
    const float*  w_cls   = (const float*)d_in[5];
    const float*  b_cls   = (const float*)d_in[6];
    const float*  w_reg   = (const float*)d_in[7];
    const float*  b_reg   = (const float*)d_in[8];

    float* out = (float*)d_out;
    char*  ws  = (char*)d_ws;
    float*              h      = (float*)(ws + WS_H);
    float*              logits = (float*)(ws + WS_LOGITS);
    float4*             boxes  = (float4*)(ws + WS_BOXES);
    unsigned int*       hist   = (unsigned int*)(ws + WS_HIST);
    unsigned int*       meta   = (unsigned int*)(ws + WS_META);
    unsigned long long* coll   = (unsigned long long*)(ws + WS_COLL);
    float4*             sboxes = (float4*)(ws + WS_SBOX);

    // zero histogram + meta (ws is poisoned 0xAA before each call)
    hipMemsetAsync(ws + WS_HIST, 0, 262144 + 256, stream);

    gemm1_kernel<<<dim3(128, 4), 256, 0, stream>>>(feats, w_bneck, b_bneck, h);
    gemm2_kernel<<<256, 256, 0, stream>>>(h, w_cls, b_cls, w_reg, b_reg, logits);
    decode_kernel<<<576, 256, 0, stream>>>(logits, ancs, out, boxes, hist);
    scan_kernel<<<1, 256, 0, stream>>>(hist, meta);
    collect_kernel<<<576, 256, 0, stream>>>(out, meta, coll, &meta[0]);
    sort_kernel<<<1, 1024, 0, stream>>>(coll, meta, boxes, sboxes);
    nms_kernel<<<1, 1024, 0, stream>>>(sboxes, out + PROP_OFF);
}

// Round 2
// 2213.162 us; speedup vs baseline: 1.2273x; 1.2273x over previous
//
#include <hip/hip_runtime.h>
#include <cstdint>
#include <cstddef>

// ---------------- problem constants ----------------
#define P_TOT    16384      // B*H*W = 4*64*64
#define CIN      1024
#define CMID     512
#define NA       9
#define NANC     147456     // P_TOT * NA
#define PRE_NMS  6000
#define POST_NMS 300
#define IOU_THR  0.7f

// output layout (floats): cls_pred | reg_pred | proposals
#define CLS_OFF  0
#define REG_OFF  147456
#define PROP_OFF 737280

// ---------------- workspace layout (bytes) ----------------
#define WS_H        0u          // 16384*512*4   = 33554432
#define WS_LOGITS   33554432u   // 16384*48*4    = 3145728
#define WS_BOXES    36700160u   // 147456*4*4    = 2359296
#define WS_HIST     39059456u   // 65536*4       = 262144
#define WS_META     39321600u   // 64*4          = 256   (meta[0]=cnt, meta[1]=T)
#define WS_COLL     39321856u   // 8192*8        = 65536
#define WS_SBOX     39387392u   // 6000*16       = 96000
#define CAP_COLL    8192

__device__ __forceinline__ int imin(int a, int b) { return a < b ? a : b; }

// async global->LDS, 16B per lane. LDS dest = wave-uniform base + lane*16,
// so the LDS pointer passed per-lane must be linear in lane index.
__device__ __forceinline__ void gld_lds16(const float* g, float* l) {
    __builtin_amdgcn_global_load_lds(
        (const __attribute__((address_space(1))) void*)g,
        (__attribute__((address_space(3))) void*)l,
        16, 0, 0);
}

// =====================================================================
// GEMM1: h[16384x512] = relu(feats[16384x1024] @ w_bneck[1024x512] + b)
// fp32 vector GEMM (fp32 REQUIRED: NMS ordering sensitive to ~1e-5 score
// noise; bf16/MFMA would reorder proposals -> absmax ~0.5).
// 128x128 tile, BK=16, 256 thr, 8x8 microtile held in 16 NAMED float4
// accumulators (spill-proof). B staged via global_load_lds (lane-linear
// [k][n] layout, zero staging regs); A staged via 8 regs (k-transpose).
// Double-buffered LDS, one barrier per K-tile.
// =====================================================================
#define AS_LD 132
__global__ __launch_bounds__(256, 2) void gemm1_kernel(
    const float* __restrict__ A, const float* __restrict__ Bw,
    const float* __restrict__ bias, float* __restrict__ C)
{
    __shared__ float As[2][16][AS_LD];   // [buf][k][m] transposed, padded
    __shared__ float Bs[2][16][128];     // [buf][k][n]  (NO pad: load_lds linearity)

    const int t  = threadIdx.x;
    const int m0 = blockIdx.x * 128;
    const int n0 = blockIdx.y * 128;
    const int tx = t & 15;               // n-dir
    const int ty = t >> 4;               // m-dir

    const int ar0 = t >> 2;              // A row in tile (0..63), second at +64
    const int ac0 = (t & 3) * 4;         // A col in tile (k)

    // B source for this lane (row t>>5 of tile, 16B at col (t&31)*4)
    const float* bsrc = Bw + (size_t)(t >> 5) * CMID + n0 + (t & 31) * 4;
    float* bdst0 = &Bs[0][0][0] + t * 4;     // lane-linear: byte off = t*16
    float* bdst1 = &Bs[1][0][0] + t * 4;
    const float* asrc0 = A + (size_t)(m0 + ar0) * CIN + ac0;
    const float* asrc1 = A + (size_t)(m0 + ar0 + 64) * CIN + ac0;

    float4 c0a{0,0,0,0}, c0b{0,0,0,0}, c1a{0,0,0,0}, c1b{0,0,0,0};
    float4 c2a{0,0,0,0}, c2b{0,0,0,0}, c3a{0,0,0,0}, c3b{0,0,0,0};
    float4 c4a{0,0,0,0}, c4b{0,0,0,0}, c5a{0,0,0,0}, c5b{0,0,0,0};
    float4 c6a{0,0,0,0}, c6b{0,0,0,0}, c7a{0,0,0,0}, c7b{0,0,0,0};

    // ---- prologue: tile 0 into buf 0 ----
    gld_lds16(bsrc, bdst0);
    gld_lds16(bsrc + 8 * CMID, bdst0 + 1024);
    float4 pa0 = *(const float4*)(asrc0);
    float4 pa1 = *(const float4*)(asrc1);
    As[0][ac0 + 0][ar0] = pa0.x; As[0][ac0 + 1][ar0] = pa0.y;
    As[0][ac0 + 2][ar0] = pa0.z; As[0][ac0 + 3][ar0] = pa0.w;
    As[0][ac0 + 0][ar0 + 64] = pa1.x; As[0][ac0 + 1][ar0 + 64] = pa1.y;
    As[0][ac0 + 2][ar0 + 64] = pa1.z; As[0][ac0 + 3][ar0 + 64] = pa1.w;
    __syncthreads();

#define FMA4(acc, s, b) { acc.x += (s)*(b).x; acc.y += (s)*(b).y; \
                          acc.z += (s)*(b).z; acc.w += (s)*(b).w; }

    for (int kt = 0; kt < 64; ++kt) {
        const int cur = kt & 1, nxt = cur ^ 1;
        if (kt < 63) {
            const int k0 = (kt + 1) * 16;
            gld_lds16(bsrc + (size_t)k0 * CMID, nxt ? bdst1 : bdst0);
            gld_lds16(bsrc + (size_t)(k0 + 8) * CMID, (nxt ? bdst1 : bdst0) + 1024);
            pa0 = *(const float4*)(asrc0 + k0);
            pa1 = *(const float4*)(asrc1 + k0);
        }
#pragma unroll
        for (int kk = 0; kk < 16; ++kk) {
            float4 a0 = *(const float4*)&As[cur][kk][ty * 4];
            float4 a1 = *(const float4*)&As[cur][kk][64 + ty * 4];
            float4 b0 = *(const float4*)&Bs[cur][kk][tx * 4];
            float4 b1 = *(const float4*)&Bs[cur][kk][64 + tx * 4];
            FMA4(c0a, a0.x, b0) FMA4(c0b, a0.x, b1)
            FMA4(c1a, a0.y, b0) FMA4(c1b, a0.y, b1)
            FMA4(c2a, a0.z, b0) FMA4(c2b, a0.z, b1)
            FMA4(c3a, a0.w, b0) FMA4(c3b, a0.w, b1)
            FMA4(c4a, a1.x, b0) FMA4(c4b, a1.x, b1)
            FMA4(c5a, a1.y, b0) FMA4(c5b, a1.y, b1)
            FMA4(c6a, a1.z, b0) FMA4(c6b, a1.z, b1)
            FMA4(c7a, a1.w, b0) FMA4(c7b, a1.w, b1)
        }
        if (kt < 63) {
            As[nxt][ac0 + 0][ar0] = pa0.x; As[nxt][ac0 + 1][ar0] = pa0.y;
            As[nxt][ac0 + 2][ar0] = pa0.z; As[nxt][ac0 + 3][ar0] = pa0.w;
            As[nxt][ac0 + 0][ar0 + 64] = pa1.x; As[nxt][ac0 + 1][ar0 + 64] = pa1.y;
            As[nxt][ac0 + 2][ar0 + 64] = pa1.z; As[nxt][ac0 + 3][ar0 + 64] = pa1.w;
        }
        __syncthreads();
    }

    const float4 bias0 = *(const float4*)(bias + n0 + tx * 4);
    const float4 bias1 = *(const float4*)(bias + n0 + 64 + tx * 4);
#define STROW(row, ca, cb) { \
    float4 o; \
    o.x = fmaxf(ca.x + bias0.x, 0.f); o.y = fmaxf(ca.y + bias0.y, 0.f); \
    o.z = fmaxf(ca.z + bias0.z, 0.f); o.w = fmaxf(ca.w + bias0.w, 0.f); \
    *(float4*)(C + (size_t)(row) * CMID + n0 + tx * 4) = o; \
    o.x = fmaxf(cb.x + bias1.x, 0.f); o.y = fmaxf(cb.y + bias1.y, 0.f); \
    o.z = fmaxf(cb.z + bias1.z, 0.f); o.w = fmaxf(cb.w + bias1.w, 0.f); \
    *(float4*)(C + (size_t)(row) * CMID + n0 + 64 + tx * 4) = o; }

    const int mr = m0 + ty * 4;
    STROW(mr + 0, c0a, c0b)  STROW(mr + 1, c1a, c1b)
    STROW(mr + 2, c2a, c2b)  STROW(mr + 3, c3a, c3b)
    STROW(mr + 64, c4a, c4b) STROW(mr + 65, c5a, c5b)
    STROW(mr + 66, c6a, c6b) STROW(mr + 67, c7a, c7b)
#undef STROW
#undef FMA4
}

// =====================================================================
// GEMM2: logits[16384 x 48(45 used)] = h[16384x512] @ [w_cls | w_reg]
// 32 pixels x 48 outs per block, 512 blocks (2/CU). px = t&31, og = t>>5
// (8 out-groups x 6 outs). Raw logits (bias added, no activation).
// =====================================================================
__global__ __launch_bounds__(256) void gemm2_kernel(
    const float* __restrict__ h,
    const float* __restrict__ wcls, const float* __restrict__ bcls,
    const float* __restrict__ wreg, const float* __restrict__ breg,
    float* __restrict__ logits)
{
    __shared__ float hS[32][33];   // padded
    __shared__ float wS[32][48];

    const int t  = threadIdx.x;
    const int p0 = blockIdx.x * 32;
    const int px = t & 31;
    const int og = t >> 5;          // 0..7 -> outs og*6 .. og*6+5

    float acc[6] = {0.f, 0.f, 0.f, 0.f, 0.f, 0.f};

    for (int kt = 0; kt < 16; ++kt) {
        const int k0 = kt * 32;
        {   // stage h tile 32x32 (1 float4 per thread)
            int r = t >> 3, c4 = (t & 7) * 4;
            float4 v = *(const float4*)(h + (size_t)(p0 + r) * CMID + k0 + c4);
            hS[r][c4 + 0] = v.x; hS[r][c4 + 1] = v.y;
            hS[r][c4 + 2] = v.z; hS[r][c4 + 3] = v.w;
        }
#pragma unroll
        for (int i = 0; i < 6; ++i) {   // stage weights 32x48
            int idx = t + i * 256;
            int kk = idx / 48, o = idx - kk * 48;
            float val = 0.f;
            if (o < 9)       val = wcls[(size_t)(k0 + kk) * 9 + o];
            else if (o < 45) val = wreg[(size_t)(k0 + kk) * 36 + (o - 9)];
            wS[kk][o] = val;
        }
        __syncthreads();
#pragma unroll 8
        for (int kk = 0; kk < 32; ++kk) {
            float hv = hS[px][kk];
            const float* wr = &wS[kk][og * 6];
            acc[0] += hv * wr[0]; acc[1] += hv * wr[1]; acc[2] += hv * wr[2];
            acc[3] += hv * wr[3]; acc[4] += hv * wr[4]; acc[5] += hv * wr[5];
        }
        __syncthreads();
    }
#pragma unroll
    for (int c = 0; c < 6; ++c) {
        int o = og * 6 + c;
        if (o < 45) {
            float bv = (o < 9) ? bcls[o] : breg[o - 9];
            logits[(size_t)(p0 + px) * 48 + o] = acc[c] + bv;
        }
    }
}

// =====================================================================
// Decode: sigmoid -> cls_pred out; raw reg -> reg_pred out; box decode
// (clip [0,1]) -> boxes ws; histogram of score upper-16 float bits.
// =====================================================================
__global__ __launch_bounds__(256) void decode_kernel(
    const float* __restrict__ logits, const float4* __restrict__ ancs,
    float* __restrict__ out, float4* __restrict__ boxes,
    unsigned int* __restrict__ hist)
{
    int i = blockIdx.x * 256 + threadIdx.x;     // < 147456
    int p = i / 9, a = i - p * 9;
    const float* lrow = logits + (size_t)p * 48;
    float lg = lrow[a];
    float score = 1.f / (1.f + expf(-lg));
    out[CLS_OFF + i] = score;

    float r0 = lrow[9 + a * 4 + 0];
    float r1 = lrow[9 + a * 4 + 1];
    float r2 = lrow[9 + a * 4 + 2];
    float r3 = lrow[9 + a * 4 + 3];
    float4 rg; rg.x = r0; rg.y = r1; rg.z = r2; rg.w = r3;
    *(float4*)(out + REG_OFF + (size_t)i * 4) = rg;

    float4 an = ancs[i];
    float cx = an.x + r0 * an.z;
    float cy = an.y + r1 * an.w;
    float ww = an.z * expf(r2);
    float hh = an.w * expf(r3);
    float4 bb;
    bb.x = fminf(fmaxf(cx - ww * 0.5f, 0.f), 1.f);
    bb.y = fminf(fmaxf(cy - hh * 0.5f, 0.f), 1.f);
    bb.z = fminf(fmaxf(cx + ww * 0.5f, 0.f), 1.f);
    bb.w = fminf(fmaxf(cy + hh * 0.5f, 0.f), 1.f);
    boxes[i] = bb;

    unsigned int sb = __float_as_uint(score);   // positive -> bit-monotone
    atomicAdd(&hist[sb >> 16], 1u);
}

// =====================================================================
// Scan: find threshold bin T = max bin with cum(>=T) >= PRE_NMS.
// =====================================================================
__global__ __launch_bounds__(256) void scan_kernel(
    const unsigned int* __restrict__ hist, unsigned int* __restrict__ meta)
{
    __shared__ unsigned int sums[256];
    __shared__ unsigned int sc[256];
    __shared__ unsigned int sc2[256];
    __shared__ int cstar;
    __shared__ unsigned int saShared;
    __shared__ int tbin;

    int t = threadIdx.x;
    if (t == 0) tbin = -1;

    unsigned int s = 0;
    int base = t << 8;
    for (int b = 0; b < 256; b += 4) {
        uint4 v = *(const uint4*)(hist + base + b);
        s += v.x + v.y + v.z + v.w;
    }
    sums[t] = s;
    __syncthreads();

    sc[t] = sums[255 - t];
    __syncthreads();
    for (int off = 1; off < 256; off <<= 1) {
        unsigned int v = sc[t];
        unsigned int add = (t >= off) ? sc[t - off] : 0u;
        __syncthreads();
        sc[t] = v + add;
        __syncthreads();
    }
    {
        unsigned int sa = (t == 255) ? 0u : sc[254 - t];
        if (sa < PRE_NMS && sa + sums[t] >= PRE_NMS) { cstar = t; saShared = sa; }
    }
    __syncthreads();

    int c = cstar;
    unsigned int SA = saShared;
    sc2[t] = hist[c * 256 + 255 - t];
    __syncthreads();
    for (int off = 1; off < 256; off <<= 1) {
        unsigned int v = sc2[t];
        unsigned int add = (t >= off) ? sc2[t - off] : 0u;
        __syncthreads();
        sc2[t] = v + add;
        __syncthreads();
    }
    {
        unsigned int si = sc2[255 - t];
        int cand = (SA + si >= PRE_NMS) ? t : -1;
        atomicMax(&tbin, cand);
    }
    __syncthreads();
    if (t == 0) meta[1] = (unsigned int)(c * 256 + tbin);
}

// =====================================================================
// Collect: all anchors with score bin >= T -> composite sort keys.
// key = score_bits<<32 | (0xFFFFFFFF - idx): descending == stable
// argsort(-score) with index tie-break (matches jnp.argsort).
// =====================================================================
__global__ __launch_bounds__(256) void collect_kernel(
    const float* __restrict__ scores, const unsigned int* __restrict__ meta,
    unsigned long long* __restrict__ coll, unsigned int* __restrict__ cnt)
{
    int i = blockIdx.x * 256 + threadIdx.x;
    unsigned int T = meta[1];
    unsigned int sb = __float_as_uint(scores[i]);
    if ((sb >> 16) >= T) {
        unsigned int pos = atomicAdd(cnt, 1u);
        if (pos < CAP_COLL)
            coll[pos] = ((unsigned long long)sb << 32) |
                        (unsigned long long)(0xFFFFFFFFu - (unsigned int)i);
    }
}

// =====================================================================
// Sort: single-block bitonic sort (descending) of up to 8192 keys in LDS
// (64KB), then gather top-6000 boxes in sorted order.
// =====================================================================
__global__ __launch_bounds__(1024) void sort_kernel(
    const unsigned long long* __restrict__ coll,
    const unsigned int* __restrict__ cnt,
    const float4* __restrict__ boxes, float4* __restrict__ sboxes)
{
    __shared__ unsigned long long keys[8192];   // 64 KB
    int t = threadIdx.x;
    unsigned int n = cnt[0];
    if (n > CAP_COLL) n = CAP_COLL;
    for (int j = t; j < 8192; j += 1024)
        keys[j] = (j < (int)n) ? coll[j] : 0ULL;
    __syncthreads();

    for (int k = 2; k <= 8192; k <<= 1) {
        for (int j = k >> 1; j > 0; j >>= 1) {
            for (int u = t; u < 4096; u += 1024) {
                int i1 = ((u & ~(j - 1)) << 1) | (u & (j - 1));
                int i2 = i1 | j;
                unsigned long long a = keys[i1], b = keys[i2];
                bool up = (i1 & k) == 0;
                bool sw = up ? (a < b) : (a > b);   // descending
                if (sw) { keys[i1] = b; keys[i2] = a; }
            }
            __syncthreads();
        }
    }
    for (int j = t; j < PRE_NMS; j += 1024) {
        unsigned int idx = 0xFFFFFFFFu - (unsigned int)(keys[j] & 0xFFFFFFFFULL);
        if (idx > NANC - 1) idx = NANC - 1;   // safety clamp
        sboxes[j] = boxes[idx];
    }
}

// =====================================================================
// NMS: single block, exact reference semantics. Candidate boxes + areas
// REGISTER-RESIDENT (6 per thread, j = t + i*1024 is wave-word aligned),
// valid bitmask in LDS cleared via __ballot (one writer per word).
// Self-suppression via (j == sl), matching keep.at[idx].set(False).
// =====================================================================
__global__ __launch_bounds__(1024) void nms_kernel(
    const float4* __restrict__ sboxes, float* __restrict__ prop)
{
    __shared__ unsigned long long valid[94];
    __shared__ int selIdx;

    int t = threadIdx.x;
    float4 bx[6]; float ba[6];
#pragma unroll
    for (int i = 0; i < 6; ++i) {
        int j = t + i * 1024;
        if (j < PRE_NMS) {
            float4 b = sboxes[j];
            bx[i] = b;
            ba[i] = (b.z - b.x) * (b.w - b.y);
        } else {
            bx[i] = make_float4(0.f, 0.f, 0.f, 0.f);
            ba[i] = 0.f;
        }
    }
    if (t < 94) valid[t] = (t == 93) ? ((1ULL << 48) - 1ULL) : ~0ULL;
    for (int j = t; j < POST_NMS * 4; j += 1024) prop[j] = 0.f;  // d_out poisoned
    __syncthreads();

    const int lane = t & 63, wv = t >> 6;
    for (int s = 0; s < POST_NMS; ++s) {
        if (t < 64) {
            int c = 0x7fffffff;
            unsigned long long w1 = valid[t];
            if (w1) c = (t << 6) + __builtin_ctzll(w1);
            if (t < 30) {
                unsigned long long w2 = valid[64 + t];
                if (w2) c = imin(c, ((64 + t) << 6) + __builtin_ctzll(w2));
            }
#pragma unroll
            for (int off = 32; off > 0; off >>= 1)
                c = imin(c, __shfl_down(c, off, 64));
            if (t == 0) selIdx = (c == 0x7fffffff) ? -1 : c;
        }
        __syncthreads();
        int sl = selIdx;
        if (sl < 0) break;

        float4 sb = sboxes[sl];               // L2-hot broadcast read
        float sa = (sb.z - sb.x) * (sb.w - sb.y);
#pragma unroll
        for (int i = 0; i < 6; ++i) {
            int j = t + i * 1024;             // == (wv + i*16)*64 + lane
            bool sup = false;
            if (j < PRE_NMS) {
                float iw = fmaxf(fminf(sb.z, bx[i].z) - fmaxf(sb.x, bx[i].x), 0.f);
                float ih = fmaxf(fminf(sb.w, bx[i].w) - fmaxf(sb.y, bx[i].y), 0.f);
                float inter = iw * ih;
                float uni = sa + ba[i] - inter;
                float iou = (uni > 0.f) ? (inter / uni) : 0.f;
                sup = (iou > IOU_THR) || (j == sl);
            }
            unsigned long long m = __ballot(sup);
            if (lane == 0 && m) valid[wv + i * 16] &= ~m;
        }
        if (t == 0) {
            prop[s * 4 + 0] = sb.x; prop[s * 4 + 1] = sb.y;
            prop[s * 4 + 2] = sb.z; prop[s * 4 + 3] = sb.w;
        }
        __syncthreads();
    }
}

// =====================================================================
extern "C" void kernel_launch(void* const* d_in, const int* in_sizes, int n_in,
                              void* d_out, int out_size, void* d_ws, size_t ws_size,
                              hipStream_t stream)
{
    const float*  feats   = (const float*)d_in[0];
    const float4* ancs    = (const float4*)d_in[1];
    // d_in[2] = ancs_valid (unused by reference)
    const float*  w_bneck = (const float*)d_in[3];
    const float*  b_bneck = (const float*)d_in[4];
    const float*  w_cls   = (const float*)d_in[5];
    const float*  b_cls   = (const float*)d_in[6];
    const float*  w_reg   = (const float*)d_in[7];
    const float*  b_reg   = (const float*)d_in[8];

    float* out = (float*)d_out;
    char*  ws  = (char*)d_ws;
    float*              h      = (float*)(ws + WS_H);
    float*              logits = (float*)(ws + WS_LOGITS);
    float4*             boxes  = (float4*)(ws + WS_BOXES);
    unsigned int*       hist   = (unsigned int*)(ws + WS_HIST);
    unsigned int*       meta   = (unsigned int*)(ws + WS_META);
    unsigned long long* coll   = (unsigned long long*)(ws + WS_COLL);
    float4*             sboxes = (float4*)(ws + WS_SBOX);

    hipMemsetAsync(ws + WS_HIST, 0, 262144 + 256, stream);

    gemm1_kernel<<<dim3(128, 4), 256, 0, stream>>>(feats, w_bneck, b_bneck, h);
    gemm2_kernel<<<512, 256, 0, stream>>>(h, w_cls, b_cls, w_reg, b_reg, logits);
    decode_kernel<<<576, 256, 0, stream>>>(logits, ancs, out, boxes, hist);
    scan_kernel<<<1, 256, 0, stream>>>(hist, meta);
    collect_kernel<<<576, 256, 0, stream>>>(out, meta, coll, &meta[0]);
    sort_kernel<<<1, 1024, 0, stream>>>(coll, meta, boxes, sboxes);
    nms_kernel<<<1, 1024, 0, stream>>>(sboxes, out + PROP_OFF);
}

// Round 3
// 1750.992 us; speedup vs baseline: 1.5512x; 1.2639x over previous
//
#include <hip/hip_runtime.h>
#include <cstdint>
#include <cstddef>

// ---------------- problem constants ----------------
#define P_TOT    16384      // B*H*W = 4*64*64
#define CIN      1024
#define CMID     512
#define NA       9
#define NANC     147456     // P_TOT * NA
#define PRE_NMS  6000
#define POST_NMS 300
#define IOU_THR  0.7f

// output layout (floats): cls_pred | reg_pred | proposals
#define CLS_OFF  0
#define REG_OFF  147456
#define PROP_OFF 737280

// ---------------- workspace layout (bytes) ----------------
#define WS_H        0u          // 16384*512*4   = 33554432
#define WS_LOGITS   33554432u   // 16384*48*4    = 3145728
#define WS_BOXES    36700160u   // 147456*4*4    = 2359296
#define WS_HIST     39059456u   // 65536*4       = 262144
#define WS_META     39321600u   // 64*4          = 256   (meta[0]=cnt, meta[1]=T)
#define WS_COLL     39321856u   // 8192*8        = 65536
#define WS_SBOX     39387392u   // 6000*16       = 96000
#define CAP_COLL    8192

__device__ __forceinline__ int imin(int a, int b) { return a < b ? a : b; }

// async global->LDS, 16B per lane. LDS dest must be wave-uniform base +
// lane*16 -> per-lane pointer linear in thread id.
__device__ __forceinline__ void gld_lds16(const float* g, float* l) {
    __builtin_amdgcn_global_load_lds(
        (const __attribute__((address_space(1))) void*)g,
        (__attribute__((address_space(3))) void*)l,
        16, 0, 0);
}

// =====================================================================
// GEMM1: h[16384x512] = relu(feats[16384x1024] @ w_bneck[1024x512] + b)
// fp32 vector GEMM (fp32 REQUIRED: NMS ordering sensitive to ~1e-6 score
// gaps; bf16/MFMA noise ~1e-4 would reorder proposals -> absmax ~0.5).
//
// R2 post-mortem: 8x8 microtile (64 acc) + full 16-deep unroll hoisted
// ~128 operand VGPRs -> allocator (targeting 4 waves/EU at 128 cap)
// spilled the accumulators every K-iter (2.9 GB scratch writes).
// R3: 4x8 microtile (32 acc), unroll 4 (operand window 48), total
// pressure ~105 VGPRs -> no spill possible at the 128 cap.
// Block tile 64x128, BK=16, 1024 blocks, double-buffered LDS,
// B staged via global_load_lds (lane-linear), A via 1 reg float4.
// =====================================================================
__global__ __launch_bounds__(256)
__attribute__((amdgpu_waves_per_eu(2, 4)))
void gemm1_kernel(
    const float* __restrict__ A, const float* __restrict__ Bw,
    const float* __restrict__ bias, float* __restrict__ C)
{
    __shared__ float As[2][16][68];    // [buf][k][m] transposed, padded
    __shared__ float Bs[2][16][128];   // [buf][k][n]  (no pad: load_lds linear)

    const int t  = threadIdx.x;
    const int m0 = blockIdx.x * 64;
    const int n0 = blockIdx.y * 128;
    const int tx = t & 15;             // n-dir: cols tx*4 and 64+tx*4
    const int ty = t >> 4;             // m-dir: rows ty*4 .. ty*4+3

    const int ar0 = t >> 2;            // A row in tile (0..63)
    const int ac0 = (t & 3) * 4;       // A col in tile (k)

    const float* asrc = A + (size_t)(m0 + ar0) * CIN + ac0;
    const float* bsrc = Bw + (size_t)(t >> 5) * CMID + n0 + (t & 31) * 4;
    float* bdst0 = &Bs[0][0][0] + t * 4;   // byte off = 16*t (lane-linear)
    float* bdst1 = &Bs[1][0][0] + t * 4;

    float4 c0a{0,0,0,0}, c0b{0,0,0,0}, c1a{0,0,0,0}, c1b{0,0,0,0};
    float4 c2a{0,0,0,0}, c2b{0,0,0,0}, c3a{0,0,0,0}, c3b{0,0,0,0};

    // ---- prologue: tile 0 into buf 0 ----
    gld_lds16(bsrc, bdst0);
    gld_lds16(bsrc + 8 * CMID, bdst0 + 1024);
    float4 pa = *(const float4*)(asrc);
    As[0][ac0 + 0][ar0] = pa.x; As[0][ac0 + 1][ar0] = pa.y;
    As[0][ac0 + 2][ar0] = pa.z; As[0][ac0 + 3][ar0] = pa.w;
    __syncthreads();

#define FMA4(acc, s, b) { acc.x += (s)*(b).x; acc.y += (s)*(b).y; \
                          acc.z += (s)*(b).z; acc.w += (s)*(b).w; }

    for (int kt = 0; kt < 64; ++kt) {
        const int cur = kt & 1, nxt = cur ^ 1;
        if (kt < 63) {
            const int k0 = (kt + 1) * 16;
            float* bd = nxt ? bdst1 : bdst0;
            gld_lds16(bsrc + (size_t)k0 * CMID, bd);
            gld_lds16(bsrc + (size_t)(k0 + 8) * CMID, bd + 1024);
            pa = *(const float4*)(asrc + k0);
        }
#pragma unroll 4
        for (int kk = 0; kk < 16; ++kk) {
            float4 a  = *(const float4*)&As[cur][kk][ty * 4];
            float4 b0 = *(const float4*)&Bs[cur][kk][tx * 4];
            float4 b1 = *(const float4*)&Bs[cur][kk][64 + tx * 4];
            FMA4(c0a, a.x, b0) FMA4(c0b, a.x, b1)
            FMA4(c1a, a.y, b0) FMA4(c1b, a.y, b1)
            FMA4(c2a, a.z, b0) FMA4(c2b, a.z, b1)
            FMA4(c3a, a.w, b0) FMA4(c3b, a.w, b1)
        }
        if (kt < 63) {
            As[nxt][ac0 + 0][ar0] = pa.x; As[nxt][ac0 + 1][ar0] = pa.y;
            As[nxt][ac0 + 2][ar0] = pa.z; As[nxt][ac0 + 3][ar0] = pa.w;
        }
        __syncthreads();
    }
#undef FMA4

    const float4 bias0 = *(const float4*)(bias + n0 + tx * 4);
    const float4 bias1 = *(const float4*)(bias + n0 + 64 + tx * 4);
#define STROW(row, ca, cb) { \
    float4 o; \
    o.x = fmaxf(ca.x + bias0.x, 0.f); o.y = fmaxf(ca.y + bias0.y, 0.f); \
    o.z = fmaxf(ca.z + bias0.z, 0.f); o.w = fmaxf(ca.w + bias0.w, 0.f); \
    *(float4*)(C + (size_t)(row) * CMID + n0 + tx * 4) = o; \
    o.x = fmaxf(cb.x + bias1.x, 0.f); o.y = fmaxf(cb.y + bias1.y, 0.f); \
    o.z = fmaxf(cb.z + bias1.z, 0.f); o.w = fmaxf(cb.w + bias1.w, 0.f); \
    *(float4*)(C + (size_t)(row) * CMID + n0 + 64 + tx * 4) = o; }

    const int mr = m0 + ty * 4;
    STROW(mr + 0, c0a, c0b)
    STROW(mr + 1, c1a, c1b)
    STROW(mr + 2, c2a, c2b)
    STROW(mr + 3, c3a, c3b)
#undef STROW
}

// =====================================================================
// GEMM2: logits[16384 x 48(45 used)] = h[16384x512] @ [w_cls | w_reg]
// 32 pixels x 48 outs per block, 512 blocks. Raw logits (bias, no act).
// =====================================================================
__global__ __launch_bounds__(256) void gemm2_kernel(
    const float* __restrict__ h,
    const float* __restrict__ wcls, const float* __restrict__ bcls,
    const float* __restrict__ wreg, const float* __restrict__ breg,
    float* __restrict__ logits)
{
    __shared__ float hS[32][33];   // padded
    __shared__ float wS[32][48];

    const int t  = threadIdx.x;
    const int p0 = blockIdx.x * 32;
    const int px = t & 31;
    const int og = t >> 5;          // 0..7 -> outs og*6 .. og*6+5

    float acc[6] = {0.f, 0.f, 0.f, 0.f, 0.f, 0.f};

    for (int kt = 0; kt < 16; ++kt) {
        const int k0 = kt * 32;
        {   // stage h tile 32x32 (1 float4 per thread)
            int r = t >> 3, c4 = (t & 7) * 4;
            float4 v = *(const float4*)(h + (size_t)(p0 + r) * CMID + k0 + c4);
            hS[r][c4 + 0] = v.x; hS[r][c4 + 1] = v.y;
            hS[r][c4 + 2] = v.z; hS[r][c4 + 3] = v.w;
        }
#pragma unroll
        for (int i = 0; i < 6; ++i) {   // stage weights 32x48
            int idx = t + i * 256;
            int kk = idx / 48, o = idx - kk * 48;
            float val = 0.f;
            if (o < 9)       val = wcls[(size_t)(k0 + kk) * 9 + o];
            else if (o < 45) val = wreg[(size_t)(k0 + kk) * 36 + (o - 9)];
            wS[kk][o] = val;
        }
        __syncthreads();
#pragma unroll 8
        for (int kk = 0; kk < 32; ++kk) {
            float hv = hS[px][kk];
            const float* wr = &wS[kk][og * 6];
            acc[0] += hv * wr[0]; acc[1] += hv * wr[1]; acc[2] += hv * wr[2];
            acc[3] += hv * wr[3]; acc[4] += hv * wr[4]; acc[5] += hv * wr[5];
        }
        __syncthreads();
    }
#pragma unroll
    for (int c = 0; c < 6; ++c) {
        int o = og * 6 + c;
        if (o < 45) {
            float bv = (o < 9) ? bcls[o] : breg[o - 9];
            logits[(size_t)(p0 + px) * 48 + o] = acc[c] + bv;
        }
    }
}

// =====================================================================
// Decode: sigmoid -> cls_pred out; raw reg -> reg_pred out; box decode
// (clip [0,1]) -> boxes ws; histogram of score upper-16 float bits.
// =====================================================================
__global__ __launch_bounds__(256) void decode_kernel(
    const float* __restrict__ logits, const float4* __restrict__ ancs,
    float* __restrict__ out, float4* __restrict__ boxes,
    unsigned int* __restrict__ hist)
{
    int i = blockIdx.x * 256 + threadIdx.x;     // < 147456
    int p = i / 9, a = i - p * 9;
    const float* lrow = logits + (size_t)p * 48;
    float lg = lrow[a];
    float score = 1.f / (1.f + expf(-lg));
    out[CLS_OFF + i] = score;

    float r0 = lrow[9 + a * 4 + 0];
    float r1 = lrow[9 + a * 4 + 1];
    float r2 = lrow[9 + a * 4 + 2];
    float r3 = lrow[9 + a * 4 + 3];
    float4 rg; rg.x = r0; rg.y = r1; rg.z = r2; rg.w = r3;
    *(float4*)(out + REG_OFF + (size_t)i * 4) = rg;

    float4 an = ancs[i];
    float cx = an.x + r0 * an.z;
    float cy = an.y + r1 * an.w;
    float ww = an.z * expf(r2);
    float hh = an.w * expf(r3);
    float4 bb;
    bb.x = fminf(fmaxf(cx - ww * 0.5f, 0.f), 1.f);
    bb.y = fminf(fmaxf(cy - hh * 0.5f, 0.f), 1.f);
    bb.z = fminf(fmaxf(cx + ww * 0.5f, 0.f), 1.f);
    bb.w = fminf(fmaxf(cy + hh * 0.5f, 0.f), 1.f);
    boxes[i] = bb;

    unsigned int sb = __float_as_uint(score);   // positive -> bit-monotone
    atomicAdd(&hist[sb >> 16], 1u);
}

// =====================================================================
// Scan: find threshold bin T = max bin with cum(>=T) >= PRE_NMS.
// =====================================================================
__global__ __launch_bounds__(256) void scan_kernel(
    const unsigned int* __restrict__ hist, unsigned int* __restrict__ meta)
{
    __shared__ unsigned int sums[256];
    __shared__ unsigned int sc[256];
    __shared__ unsigned int sc2[256];
    __shared__ int cstar;
    __shared__ unsigned int saShared;
    __shared__ int tbin;

    int t = threadIdx.x;
    if (t == 0) tbin = -1;

    unsigned int s = 0;
    int base = t << 8;
    for (int b = 0; b < 256; b += 4) {
        uint4 v = *(const uint4*)(hist + base + b);
        s += v.x + v.y + v.z + v.w;
    }
    sums[t] = s;
    __syncthreads();

    sc[t] = sums[255 - t];
    __syncthreads();
    for (int off = 1; off < 256; off <<= 1) {
        unsigned int v = sc[t];
        unsigned int add = (t >= off) ? sc[t - off] : 0u;
        __syncthreads();
        sc[t] = v + add;
        __syncthreads();
    }
    {
        unsigned int sa = (t == 255) ? 0u : sc[254 - t];
        if (sa < PRE_NMS && sa + sums[t] >= PRE_NMS) { cstar = t; saShared = sa; }
    }
    __syncthreads();

    int c = cstar;
    unsigned int SA = saShared;
    sc2[t] = hist[c * 256 + 255 - t];
    __syncthreads();
    for (int off = 1; off < 256; off <<= 1) {
        unsigned int v = sc2[t];
        unsigned int add = (t >= off) ? sc2[t - off] : 0u;
        __syncthreads();
        sc2[t] = v + add;
        __syncthreads();
    }
    {
        unsigned int si = sc2[255 - t];
        int cand = (SA + si >= PRE_NMS) ? t : -1;
        atomicMax(&tbin, cand);
    }
    __syncthreads();
    if (t == 0) meta[1] = (unsigned int)(c * 256 + tbin);
}

// =====================================================================
// Collect: all anchors with score bin >= T -> composite sort keys.
// key = score_bits<<32 | (0xFFFFFFFF - idx): descending == stable
// argsort(-score) with index tie-break (matches jnp.argsort).
// =====================================================================
__global__ __launch_bounds__(256) void collect_kernel(
    const float* __restrict__ scores, const unsigned int* __restrict__ meta,
    unsigned long long* __restrict__ coll, unsigned int* __restrict__ cnt)
{
    int i = blockIdx.x * 256 + threadIdx.x;
    unsigned int T = meta[1];
    unsigned int sb = __float_as_uint(scores[i]);
    if ((sb >> 16) >= T) {
        unsigned int pos = atomicAdd(cnt, 1u);
        if (pos < CAP_COLL)
            coll[pos] = ((unsigned long long)sb << 32) |
                        (unsigned long long)(0xFFFFFFFFu - (unsigned int)i);
    }
}

// =====================================================================
// Sort: single-block bitonic sort (descending) of up to 8192 keys in LDS
// (64KB), then gather top-6000 boxes in sorted order.
// =====================================================================
__global__ __launch_bounds__(1024) void sort_kernel(
    const unsigned long long* __restrict__ coll,
    const unsigned int* __restrict__ cnt,
    const float4* __restrict__ boxes, float4* __restrict__ sboxes)
{
    __shared__ unsigned long long keys[8192];   // 64 KB
    int t = threadIdx.x;
    unsigned int n = cnt[0];
    if (n > CAP_COLL) n = CAP_COLL;
    for (int j = t; j < 8192; j += 1024)
        keys[j] = (j < (int)n) ? coll[j] : 0ULL;
    __syncthreads();

    for (int k = 2; k <= 8192; k <<= 1) {
        for (int j = k >> 1; j > 0; j >>= 1) {
            for (int u = t; u < 4096; u += 1024) {
                int i1 = ((u & ~(j - 1)) << 1) | (u & (j - 1));
                int i2 = i1 | j;
                unsigned long long a = keys[i1], b = keys[i2];
                bool up = (i1 & k) == 0;
                bool sw = up ? (a < b) : (a > b);   // descending
                if (sw) { keys[i1] = b; keys[i2] = a; }
            }
            __syncthreads();
        }
    }
    for (int j = t; j < PRE_NMS; j += 1024) {
        unsigned int idx = 0xFFFFFFFFu - (unsigned int)(keys[j] & 0xFFFFFFFFULL);
        if (idx > NANC - 1) idx = NANC - 1;   // safety clamp
        sboxes[j] = boxes[idx];
    }
}

// =====================================================================
// NMS: single block, 256 threads, FULLY register-resident. 24 boxes per
// thread (j = i*256 + t), validity = 24-bit register mask. Per round:
// ctz -> shfl-min -> cross-wave LDS min (2 barriers), then <=24
// predicated IoUs (whole-wave execz skip when no valid bits).
// Exact reference semantics: first-valid = min index (jnp.argmax of
// bool), self-suppression via (j == g) (keep.at[idx].set(False)).
// =====================================================================
__global__ __launch_bounds__(256)
__attribute__((amdgpu_waves_per_eu(1, 2)))
void nms_kernel(const float4* __restrict__ sboxes, float* __restrict__ prop)
{
    __shared__ int warr[4];
    __shared__ float selb[5];

    const int t = threadIdx.x;
    const int lane = t & 63, wv = t >> 6;

    float x1[24], y1[24], x2[24], y2[24], ar[24];
    unsigned int mask = 0;
#pragma unroll
    for (int i = 0; i < 24; ++i) {
        int j = i * 256 + t;
        if (j < PRE_NMS) {
            float4 b = sboxes[j];
            x1[i] = b.x; y1[i] = b.y; x2[i] = b.z; y2[i] = b.w;
            ar[i] = (b.z - b.x) * (b.w - b.y);
            mask |= (1u << i);
        } else {
            x1[i] = y1[i] = x2[i] = y2[i] = ar[i] = 0.f;
        }
    }
    for (int j = t; j < POST_NMS * 4; j += 256) prop[j] = 0.f;  // d_out poisoned
    __syncthreads();

    for (int s = 0; s < POST_NMS; ++s) {
        // min surviving global index: j = i*256 + t  ->  ctz(mask)*256 + t
        int c = mask ? (int)(__builtin_ctz(mask) * 256 + t) : 0x7fffffff;
#pragma unroll
        for (int off = 32; off > 0; off >>= 1)
            c = imin(c, __shfl_down(c, off, 64));
        if (lane == 0) warr[wv] = c;
        __syncthreads();
        int g = imin(imin(warr[0], warr[1]), imin(warr[2], warr[3]));
        if (g == 0x7fffffff) break;   // uniform; remaining rows stay zero

        if ((g & 255) == t) {         // owner broadcasts selected box
            int i = g >> 8;
            selb[0] = x1[i]; selb[1] = y1[i]; selb[2] = x2[i];
            selb[3] = y2[i]; selb[4] = ar[i];
            prop[s * 4 + 0] = x1[i]; prop[s * 4 + 1] = y1[i];
            prop[s * 4 + 2] = x2[i]; prop[s * 4 + 3] = y2[i];
        }
        __syncthreads();
        float sx1 = selb[0], sy1 = selb[1], sx2 = selb[2], sy2 = selb[3];
        float sa = selb[4];
#pragma unroll
        for (int i = 0; i < 24; ++i) {
            if (mask & (1u << i)) {
                float iw = fmaxf(fminf(sx2, x2[i]) - fmaxf(sx1, x1[i]), 0.f);
                float ih = fmaxf(fminf(sy2, y2[i]) - fmaxf(sy1, y1[i]), 0.f);
                float inter = iw * ih;
                float uni = sa + ar[i] - inter;
                float iou = (uni > 0.f) ? (inter / uni) : 0.f;
                if (iou > IOU_THR || (i * 256 + t) == g) mask &= ~(1u << i);
            }
        }
        // next round: warr write is after this round's barrier #2 (above);
        // selb re-write is after next round's barrier #1 -> race-free.
    }
}

// =====================================================================
extern "C" void kernel_launch(void* const* d_in, const int* in_sizes, int n_in,
                              void* d_out, int out_size, void* d_ws, size_t ws_size,
                              hipStream_t stream)
{
    const float*  feats   = (const float*)d_in[0];
    const float4* ancs    = (const float4*)d_in[1];
    // d_in[2] = ancs_valid (unused by reference)
    const float*  w_bneck = (const float*)d_in[3];
    const float*  b_bneck = (const float*)d_in[4];
    const float*  w_cls   = (const float*)d_in[5];
    const float*  b_cls   = (const float*)d_in[6];
    const float*  w_reg   = (const float*)d_in[7];
    const float*  b_reg   = (const float*)d_in[8];

    float* out = (float*)d_out;
    char*  ws  = (char*)d_ws;
    float*              h      = (float*)(ws + WS_H);
    float*              logits = (float*)(ws + WS_LOGITS);
    float4*             boxes  = (float4*)(ws + WS_BOXES);
    unsigned int*       hist   = (unsigned int*)(ws + WS_HIST);
    unsigned int*       meta   = (unsigned int*)(ws + WS_META);
    unsigned long long* coll   = (unsigned long long*)(ws + WS_COLL);
    float4*             sboxes = (float4*)(ws + WS_SBOX);

    hipMemsetAsync(ws + WS_HIST, 0, 262144 + 256, stream);

    gemm1_kernel<<<dim3(256, 4), 256, 0, stream>>>(feats, w_bneck, b_bneck, h);
    gemm2_kernel<<<512, 256, 0, stream>>>(h, w_cls, b_cls, w_reg, b_reg, logits);
    decode_kernel<<<576, 256, 0, stream>>>(logits, ancs, out, boxes, hist);
    scan_kernel<<<1, 256, 0, stream>>>(hist, meta);
    collect_kernel<<<576, 256, 0, stream>>>(out, meta, coll, &meta[0]);
    sort_kernel<<<1, 1024, 0, stream>>>(coll, meta, boxes, sboxes);
    nms_kernel<<<1, 256, 0, stream>>>(sboxes, out + PROP_OFF);
}

// Round 5
// 1063.137 us; speedup vs baseline: 2.5549x; 1.6470x over previous
//
#include <hip/hip_runtime.h>
#include <cstdint>
#include <cstddef>

// ---------------- problem constants ----------------
#define P_TOT    16384      // B*H*W = 4*64*64
#define CIN      1024
#define CMID     512
#define NA       9
#define NANC     147456     // P_TOT * NA
#define PRE_NMS  6000
#define POST_NMS 300
#define IOU_THR  0.7f
#define NWORDS   94         // ceil(6000/64)

// output layout (floats): cls_pred | reg_pred | proposals
#define CLS_OFF  0
#define REG_OFF  147456
#define PROP_OFF 737280

// ---------------- workspace layout (bytes) ----------------
// WS_MASK aliases WS_H: h is dead after gemm2, nmsmat runs after sort.
// Keeps total ws use at the R3-proven ~39.5 MB.
#define WS_H        0u          // 16384*512*4   = 33554432
#define WS_MASK     0u          // 6000*94*8     = 4512000 (aliases h)
#define WS_LOGITS   33554432u   // 16384*48*4    = 3145728
#define WS_BOXES    36700160u   // 147456*4*4    = 2359296
#define WS_HIST     39059456u   // 65536*4       = 262144
#define WS_META     39321600u   // 64*4          = 256   (meta[0]=cnt, meta[1]=T)
#define WS_COLL     39321856u   // 8192*8        = 65536
#define WS_SBOX     39387392u   // 6000*16       = 96000  -> end ~39.5 MB
#define CAP_COLL    8192

__device__ __forceinline__ int imin(int a, int b) { return a < b ? a : b; }

// async global->LDS, 16B per lane. LDS dest must be wave-uniform base +
// lane*16 -> per-lane pointer linear in thread id.
__device__ __forceinline__ void gld_lds16(const float* g, float* l) {
    __builtin_amdgcn_global_load_lds(
        (const __attribute__((address_space(1))) void*)g,
        (__attribute__((address_space(3))) void*)l,
        16, 0, 0);
}

// =====================================================================
// GEMM1: h[16384x512] = relu(feats[16384x1024] @ w_bneck[1024x512] + b)
// fp32 vector GEMM (fp32 REQUIRED: NMS ordering sensitive to ~1e-6 score
// gaps; bf16/MFMA noise would reorder proposals -> absmax ~0.5).
// 4x8 microtile (32 acc VGPRs), unroll 4, 64x128 block tile, BK=16,
// double-buffered LDS, B via global_load_lds. (unchanged from R3)
// =====================================================================
__global__ __launch_bounds__(256)
__attribute__((amdgpu_waves_per_eu(2, 4)))
void gemm1_kernel(
    const float* __restrict__ A, const float* __restrict__ Bw,
    const float* __restrict__ bias, float* __restrict__ C)
{
    __shared__ float As[2][16][68];    // [buf][k][m] transposed, padded
    __shared__ float Bs[2][16][128];   // [buf][k][n]  (no pad: load_lds linear)

    const int t  = threadIdx.x;
    const int m0 = blockIdx.x * 64;
    const int n0 = blockIdx.y * 128;
    const int tx = t & 15;             // n-dir: cols tx*4 and 64+tx*4
    const int ty = t >> 4;             // m-dir: rows ty*4 .. ty*4+3

    const int ar0 = t >> 2;            // A row in tile (0..63)
    const int ac0 = (t & 3) * 4;       // A col in tile (k)

    const float* asrc = A + (size_t)(m0 + ar0) * CIN + ac0;
    const float* bsrc = Bw + (size_t)(t >> 5) * CMID + n0 + (t & 31) * 4;
    float* bdst0 = &Bs[0][0][0] + t * 4;   // byte off = 16*t (lane-linear)
    float* bdst1 = &Bs[1][0][0] + t * 4;

    float4 c0a{0,0,0,0}, c0b{0,0,0,0}, c1a{0,0,0,0}, c1b{0,0,0,0};
    float4 c2a{0,0,0,0}, c2b{0,0,0,0}, c3a{0,0,0,0}, c3b{0,0,0,0};

    gld_lds16(bsrc, bdst0);
    gld_lds16(bsrc + 8 * CMID, bdst0 + 1024);
    float4 pa = *(const float4*)(asrc);
    As[0][ac0 + 0][ar0] = pa.x; As[0][ac0 + 1][ar0] = pa.y;
    As[0][ac0 + 2][ar0] = pa.z; As[0][ac0 + 3][ar0] = pa.w;
    __syncthreads();

#define FMA4(acc, s, b) { acc.x += (s)*(b).x; acc.y += (s)*(b).y; \
                          acc.z += (s)*(b).z; acc.w += (s)*(b).w; }

    for (int kt = 0; kt < 64; ++kt) {
        const int cur = kt & 1, nxt = cur ^ 1;
        if (kt < 63) {
            const int k0 = (kt + 1) * 16;
            float* bd = nxt ? bdst1 : bdst0;
            gld_lds16(bsrc + (size_t)k0 * CMID, bd);
            gld_lds16(bsrc + (size_t)(k0 + 8) * CMID, bd + 1024);
            pa = *(const float4*)(asrc + k0);
        }
#pragma unroll 4
        for (int kk = 0; kk < 16; ++kk) {
            float4 a  = *(const float4*)&As[cur][kk][ty * 4];
            float4 b0 = *(const float4*)&Bs[cur][kk][tx * 4];
            float4 b1 = *(const float4*)&Bs[cur][kk][64 + tx * 4];
            FMA4(c0a, a.x, b0) FMA4(c0b, a.x, b1)
            FMA4(c1a, a.y, b0) FMA4(c1b, a.y, b1)
            FMA4(c2a, a.z, b0) FMA4(c2b, a.z, b1)
            FMA4(c3a, a.w, b0) FMA4(c3b, a.w, b1)
        }
        if (kt < 63) {
            As[nxt][ac0 + 0][ar0] = pa.x; As[nxt][ac0 + 1][ar0] = pa.y;
            As[nxt][ac0 + 2][ar0] = pa.z; As[nxt][ac0 + 3][ar0] = pa.w;
        }
        __syncthreads();
    }
#undef FMA4

    const float4 bias0 = *(const float4*)(bias + n0 + tx * 4);
    const float4 bias1 = *(const float4*)(bias + n0 + 64 + tx * 4);
#define STROW(row, ca, cb) { \
    float4 o; \
    o.x = fmaxf(ca.x + bias0.x, 0.f); o.y = fmaxf(ca.y + bias0.y, 0.f); \
    o.z = fmaxf(ca.z + bias0.z, 0.f); o.w = fmaxf(ca.w + bias0.w, 0.f); \
    *(float4*)(C + (size_t)(row) * CMID + n0 + tx * 4) = o; \
    o.x = fmaxf(cb.x + bias1.x, 0.f); o.y = fmaxf(cb.y + bias1.y, 0.f); \
    o.z = fmaxf(cb.z + bias1.z, 0.f); o.w = fmaxf(cb.w + bias1.w, 0.f); \
    *(float4*)(C + (size_t)(row) * CMID + n0 + 64 + tx * 4) = o; }

    const int mr = m0 + ty * 4;
    STROW(mr + 0, c0a, c0b)
    STROW(mr + 1, c1a, c1b)
    STROW(mr + 2, c2a, c2b)
    STROW(mr + 3, c3a, c3b)
#undef STROW
}

// =====================================================================
// GEMM2: logits[16384 x 48(45 used)] = h[16384x512] @ [w_cls | w_reg]
// =====================================================================
__global__ __launch_bounds__(256) void gemm2_kernel(
    const float* __restrict__ h,
    const float* __restrict__ wcls, const float* __restrict__ bcls,
    const float* __restrict__ wreg, const float* __restrict__ breg,
    float* __restrict__ logits)
{
    __shared__ float hS[32][33];   // padded
    __shared__ float wS[32][48];

    const int t  = threadIdx.x;
    const int p0 = blockIdx.x * 32;
    const int px = t & 31;
    const int og = t >> 5;          // 0..7 -> outs og*6 .. og*6+5

    float acc[6] = {0.f, 0.f, 0.f, 0.f, 0.f, 0.f};

    for (int kt = 0; kt < 16; ++kt) {
        const int k0 = kt * 32;
        {   // stage h tile 32x32 (1 float4 per thread)
            int r = t >> 3, c4 = (t & 7) * 4;
            float4 v = *(const float4*)(h + (size_t)(p0 + r) * CMID + k0 + c4);
            hS[r][c4 + 0] = v.x; hS[r][c4 + 1] = v.y;
            hS[r][c4 + 2] = v.z; hS[r][c4 + 3] = v.w;
        }
#pragma unroll
        for (int i = 0; i < 6; ++i) {   // stage weights 32x48
            int idx = t + i * 256;
            int kk = idx / 48, o = idx - kk * 48;
            float val = 0.f;
            if (o < 9)       val = wcls[(size_t)(k0 + kk) * 9 + o];
            else if (o < 45) val = wreg[(size_t)(k0 + kk) * 36 + (o - 9)];
            wS[kk][o] = val;
        }
        __syncthreads();
#pragma unroll 8
        for (int kk = 0; kk < 32; ++kk) {
            float hv = hS[px][kk];
            const float* wr = &wS[kk][og * 6];
            acc[0] += hv * wr[0]; acc[1] += hv * wr[1]; acc[2] += hv * wr[2];
            acc[3] += hv * wr[3]; acc[4] += hv * wr[4]; acc[5] += hv * wr[5];
        }
        __syncthreads();
    }
#pragma unroll
    for (int c = 0; c < 6; ++c) {
        int o = og * 6 + c;
        if (o < 45) {
            float bv = (o < 9) ? bcls[o] : breg[o - 9];
            logits[(size_t)(p0 + px) * 48 + o] = acc[c] + bv;
        }
    }
}

// =====================================================================
// Decode: sigmoid -> cls_pred out; raw reg -> reg_pred out; box decode
// (clip [0,1]) -> boxes ws; histogram of score upper-16 float bits.
// =====================================================================
__global__ __launch_bounds__(256) void decode_kernel(
    const float* __restrict__ logits, const float4* __restrict__ ancs,
    float* __restrict__ out, float4* __restrict__ boxes,
    unsigned int* __restrict__ hist)
{
    int i = blockIdx.x * 256 + threadIdx.x;     // < 147456
    int p = i / 9, a = i - p * 9;
    const float* lrow = logits + (size_t)p * 48;
    float lg = lrow[a];
    float score = 1.f / (1.f + expf(-lg));
    out[CLS_OFF + i] = score;

    float r0 = lrow[9 + a * 4 + 0];
    float r1 = lrow[9 + a * 4 + 1];
    float r2 = lrow[9 + a * 4 + 2];
    float r3 = lrow[9 + a * 4 + 3];
    float4 rg; rg.x = r0; rg.y = r1; rg.z = r2; rg.w = r3;
    *(float4*)(out + REG_OFF + (size_t)i * 4) = rg;

    float4 an = ancs[i];
    float cx = an.x + r0 * an.z;
    float cy = an.y + r1 * an.w;
    float ww = an.z * expf(r2);
    float hh = an.w * expf(r3);
    float4 bb;
    bb.x = fminf(fmaxf(cx - ww * 0.5f, 0.f), 1.f);
    bb.y = fminf(fmaxf(cy - hh * 0.5f, 0.f), 1.f);
    bb.z = fminf(fmaxf(cx + ww * 0.5f, 0.f), 1.f);
    bb.w = fminf(fmaxf(cy + hh * 0.5f, 0.f), 1.f);
    boxes[i] = bb;

    unsigned int sb = __float_as_uint(score);   // positive -> bit-monotone
    atomicAdd(&hist[sb >> 16], 1u);
}

// =====================================================================
// Scan: find threshold bin T = max bin with cum(>=T) >= PRE_NMS.
// =====================================================================
__global__ __launch_bounds__(256) void scan_kernel(
    const unsigned int* __restrict__ hist, unsigned int* __restrict__ meta)
{
    __shared__ unsigned int sums[256];
    __shared__ unsigned int sc[256];
    __shared__ unsigned int sc2[256];
    __shared__ int cstar;
    __shared__ unsigned int saShared;
    __shared__ int tbin;

    int t = threadIdx.x;
    if (t == 0) tbin = -1;

    unsigned int s = 0;
    int base = t << 8;
    for (int b = 0; b < 256; b += 4) {
        uint4 v = *(const uint4*)(hist + base + b);
        s += v.x + v.y + v.z + v.w;
    }
    sums[t] = s;
    __syncthreads();

    sc[t] = sums[255 - t];
    __syncthreads();
    for (int off = 1; off < 256; off <<= 1) {
        unsigned int v = sc[t];
        unsigned int add = (t >= off) ? sc[t - off] : 0u;
        __syncthreads();
        sc[t] = v + add;
        __syncthreads();
    }
    {
        unsigned int sa = (t == 255) ? 0u : sc[254 - t];
        if (sa < PRE_NMS && sa + sums[t] >= PRE_NMS) { cstar = t; saShared = sa; }
    }
    __syncthreads();

    int c = cstar;
    unsigned int SA = saShared;
    sc2[t] = hist[c * 256 + 255 - t];
    __syncthreads();
    for (int off = 1; off < 256; off <<= 1) {
        unsigned int v = sc2[t];
        unsigned int add = (t >= off) ? sc2[t - off] : 0u;
        __syncthreads();
        sc2[t] = v + add;
        __syncthreads();
    }
    {
        unsigned int si = sc2[255 - t];
        int cand = (SA + si >= PRE_NMS) ? t : -1;
        atomicMax(&tbin, cand);
    }
    __syncthreads();
    if (t == 0) meta[1] = (unsigned int)(c * 256 + tbin);
}

// =====================================================================
// Collect: all anchors with score bin >= T -> composite sort keys.
// key = score_bits<<32 | (0xFFFFFFFF - idx): descending == stable
// argsort(-score) with index tie-break (matches jnp.argsort).
// =====================================================================
__global__ __launch_bounds__(256) void collect_kernel(
    const float* __restrict__ scores, const unsigned int* __restrict__ meta,
    unsigned long long* __restrict__ coll, unsigned int* __restrict__ cnt)
{
    int i = blockIdx.x * 256 + threadIdx.x;
    unsigned int T = meta[1];
    unsigned int sb = __float_as_uint(scores[i]);
    if ((sb >> 16) >= T) {
        unsigned int pos = atomicAdd(cnt, 1u);
        if (pos < CAP_COLL)
            coll[pos] = ((unsigned long long)sb << 32) |
                        (unsigned long long)(0xFFFFFFFFu - (unsigned int)i);
    }
}

// =====================================================================
// Sort: single-block bitonic sort (descending) of up to 8192 keys in LDS
// (64KB), then gather top-6000 boxes in sorted order.
// =====================================================================
__global__ __launch_bounds__(1024) void sort_kernel(
    const unsigned long long* __restrict__ coll,
    const unsigned int* __restrict__ cnt,
    const float4* __restrict__ boxes, float4* __restrict__ sboxes)
{
    __shared__ unsigned long long keys[8192];   // 64 KB
    int t = threadIdx.x;
    unsigned int n = cnt[0];
    if (n > CAP_COLL) n = CAP_COLL;
    for (int j = t; j < 8192; j += 1024)
        keys[j] = (j < (int)n) ? coll[j] : 0ULL;
    __syncthreads();

    for (int k = 2; k <= 8192; k <<= 1) {
        for (int j = k >> 1; j > 0; j >>= 1) {
            for (int u = t; u < 4096; u += 1024) {
                int i1 = ((u & ~(j - 1)) << 1) | (u & (j - 1));
                int i2 = i1 | j;
                unsigned long long a = keys[i1], b = keys[i2];
                bool up = (i1 & k) == 0;
                bool sw = up ? (a < b) : (a > b);   // descending
                if (sw) { keys[i1] = b; keys[i2] = a; }
            }
            __syncthreads();
        }
    }
    for (int j = t; j < PRE_NMS; j += 1024) {
        unsigned int idx = 0xFFFFFFFFu - (unsigned int)(keys[j] & 0xFFFFFFFFULL);
        if (idx > NANC - 1) idx = NANC - 1;   // safety clamp
        sboxes[j] = boxes[idx];
    }
}

// =====================================================================
// NMS matrix build (torchvision-style): strict-upper suppression bitmask.
// mask[r][cb] bit i set  <=>  j = cb*64+i, j > r, IoU(r,j) > 0.7.
// Strict-upper == reference's bidirectional suppression because the
// selection order is increasing index (boxes sorted by score): any j < i
// is already decided when i is selected. IEEE divide kept (boundary
// inter/union > 0.7 must match numpy bit-exactly).
// Grid (94,94), 64 thr; blocks with cb < rb exit (rows' lower words are
// never read by resolve).
// =====================================================================
__global__ __launch_bounds__(64) void nmsmat_kernel(
    const float4* __restrict__ sboxes, unsigned long long* __restrict__ mask)
{
    const int rb = blockIdx.x, cb = blockIdx.y;
    if (cb < rb) return;
    __shared__ float cx1[64], cy1[64], cx2[64], cy2[64], car[64];

    const int t = threadIdx.x;
    const int c = cb * 64 + t;
    float4 b = (c < PRE_NMS) ? sboxes[c] : make_float4(0.f, 0.f, 0.f, 0.f);
    cx1[t] = b.x; cy1[t] = b.y; cx2[t] = b.z; cy2[t] = b.w;
    car[t] = (b.z - b.x) * (b.w - b.y);
    __syncthreads();

    const int r = rb * 64 + t;
    if (r >= PRE_NMS) return;
    const float4 rbx = sboxes[r];
    const float ra = (rbx.z - rbx.x) * (rbx.w - rbx.y);

    unsigned long long w = 0ULL;
#pragma unroll 8
    for (int i = 0; i < 64; ++i) {
        int j = cb * 64 + i;
        float iw = fmaxf(fminf(rbx.z, cx2[i]) - fmaxf(rbx.x, cx1[i]), 0.f);
        float ih = fmaxf(fminf(rbx.w, cy2[i]) - fmaxf(rbx.y, cy1[i]), 0.f);
        float inter = iw * ih;
        float uni = ra + car[i] - inter;
        float iou = (uni > 0.f) ? (inter / uni) : 0.f;   // dummy j>=6000 -> 0
        if (iou > IOU_THR && j > r) w |= (1ULL << i);
    }
    mask[(size_t)r * NWORDS + cb] = w;
}

// =====================================================================
// NMS resolve: ONE wave, no barriers, valid bitmask in REGISTERS
// (lane t owns words 2t and 2t+1). Per selection: ballot+ctz+shfl finds
// min surviving index, one predicated global row load ANDs out
// suppressed bits (~1 L2 latency per selection).
// R4 BUG FIXED: __ballot takes int -> (v0|v1) was TRUNCATED to low 32
// bits, dropping lanes whose survivors were all in bits 32..63. Now an
// explicit != 0ULL comparison.
// =====================================================================
__global__ __launch_bounds__(64) void nmsresolve_kernel(
    const float4* __restrict__ sboxes,
    const unsigned long long* __restrict__ mask,
    float* __restrict__ prop)
{
    const int t = threadIdx.x;      // one wave
    // zero all proposal rows (d_out is poisoned); single wave => lockstep,
    // completes before the loop below, no barrier needed
    for (int j = t; j < POST_NMS * 4; j += 64) prop[j] = 0.f;

    const int w0 = 2 * t, w1 = 2 * t + 1;
    // init valid words (6000 = 93*64 + 48)
    unsigned long long v0 = 0ULL, v1 = 0ULL;
    if (w0 < 93) v0 = ~0ULL; else if (w0 == 93) v0 = (1ULL << 48) - 1ULL;
    if (w1 < 93) v1 = ~0ULL; else if (w1 == 93) v1 = (1ULL << 48) - 1ULL;

    int cnt = 0;
    while (cnt < POST_NMS) {
        int c = 0x7fffffff;
        if (v0) c = (w0 << 6) + __builtin_ctzll(v0);
        else if (v1) c = (w1 << 6) + __builtin_ctzll(v1);
        unsigned long long bal = __ballot((v0 | v1) != 0ULL);   // FIXED
        if (!bal) break;                          // uniform: all decided
        int F = __builtin_ctzll(bal);             // lowest lane = lowest words
        int g = __shfl(c, F, 64);                 // min surviving index
        const int wg = g >> 6, bg = g & 63;

        if (t == 0) {                             // emit proposal row
            float4 bb = sboxes[g];
            *(float4*)(prop + cnt * 4) = bb;
        }
        // suppress: row g valid only for words >= wg (strict upper)
        const unsigned long long* row = mask + (size_t)g * NWORDS;
        unsigned long long m0 = (w0 >= wg) ? row[w0] : 0ULL;
        unsigned long long m1 = (w1 >= wg) ? row[w1] : 0ULL;
        v0 &= ~m0; v1 &= ~m1;
        if (w0 == wg) v0 &= ~(1ULL << bg);        // self-removal
        if (w1 == wg) v1 &= ~(1ULL << bg);
        ++cnt;
    }
}

// =====================================================================
extern "C" void kernel_launch(void* const* d_in, const int* in_sizes, int n_in,
                              void* d_out, int out_size, void* d_ws, size_t ws_size,
                              hipStream_t stream)
{
    const float*  feats   = (const float*)d_in[0];
    const float4* ancs    = (const float4*)d_in[1];
    // d_in[2] = ancs_valid (unused by reference)
    const float*  w_bneck = (const float*)d_in[3];
    const float*  b_bneck = (const float*)d_in[4];
    const float*  w_cls   = (const float*)d_in[5];
    const float*  b_cls   = (const float*)d_in[6];
    const float*  w_reg   = (const float*)d_in[7];
    const float*  b_reg   = (const float*)d_in[8];

    float* out = (float*)d_out;
    char*  ws  = (char*)d_ws;
    float*              h      = (float*)(ws + WS_H);
    float*              logits = (float*)(ws + WS_LOGITS);
    float4*             boxes  = (float4*)(ws + WS_BOXES);
    unsigned int*       hist   = (unsigned int*)(ws + WS_HIST);
    unsigned int*       meta   = (unsigned int*)(ws + WS_META);
    unsigned long long* coll   = (unsigned long long*)(ws + WS_COLL);
    float4*             sboxes = (float4*)(ws + WS_SBOX);
    unsigned long long* mask   = (unsigned long long*)(ws + WS_MASK); // aliases h

    hipMemsetAsync(ws + WS_HIST, 0, 262144 + 256, stream);

    gemm1_kernel<<<dim3(256, 4), 256, 0, stream>>>(feats, w_bneck, b_bneck, h);
    gemm2_kernel<<<512, 256, 0, stream>>>(h, w_cls, b_cls, w_reg, b_reg, logits);
    decode_kernel<<<576, 256, 0, stream>>>(logits, ancs, out, boxes, hist);
    scan_kernel<<<1, 256, 0, stream>>>(hist, meta);
    collect_kernel<<<576, 256, 0, stream>>>(out, meta, coll, &meta[0]);
    sort_kernel<<<1, 1024, 0, stream>>>(coll, meta, boxes, sboxes);
    nmsmat_kernel<<<dim3(94, 94), 64, 0, stream>>>(sboxes, mask);
    nmsresolve_kernel<<<1, 64, 0, stream>>>(sboxes, mask, out + PROP_OFF);
}

// Round 6
// 754.722 us; speedup vs baseline: 3.5990x; 1.4086x over previous
//
#include <hip/hip_runtime.h>
#include <cstdint>
#include <cstddef>

// ---------------- problem constants ----------------
#define P_TOT    16384      // B*H*W = 4*64*64
#define CIN      1024
#define CMID     512
#define NA       9
#define NANC     147456     // P_TOT * NA
#define PRE_NMS  6000
#define POST_NMS 300
#define IOU_THR  0.7f
#define NWORDS   94         // ceil(6000/64)
#define NHCOPY   64         // histogram copies (contention spreading)

// output layout (floats): cls_pred | reg_pred | proposals
#define CLS_OFF  0
#define REG_OFF  147456
#define PROP_OFF 737280

// ---------------- workspace layout (bytes) ----------------
// Aliasing into the dead h region (h: 33.5 MB, dead after gemm2):
//   WS_MASK  @ 0       (4.5 MB, written by nmsmat, after sort)
//   WS_HISTN @ 8 MB    (16 MB, 64 histogram copies, written by decode)
// Lifetimes: gemm2 reads h -> decode writes HISTN -> hreduce reads HISTN
// -> ... -> nmsmat writes MASK (HISTN dead by then). No conflicts.
#define WS_H        0u          // 16384*512*4   = 33554432
#define WS_MASK     0u          // 6000*94*8     = 4512000   (aliases h)
#define WS_HISTN    8388608u    // 64*65536*4    = 16777216  (aliases h)
#define WS_LOGITS   33554432u   // 16384*48*4    = 3145728
#define WS_BOXES    36700160u   // 147456*4*4    = 2359296
#define WS_HIST     39059456u   // 65536*4       = 262144
#define WS_META     39321600u   // 64*4          = 256   (meta[0]=cnt, meta[1]=T)
#define WS_COLL     39321856u   // 8192*8        = 65536
#define WS_SBOX     39387392u   // 6000*16       = 96000  -> end ~39.5 MB
#define CAP_COLL    8192

__device__ __forceinline__ int imin(int a, int b) { return a < b ? a : b; }

// async global->LDS, 16B per lane. LDS dest must be wave-uniform base +
// lane*16 -> per-lane pointer linear in thread id.
__device__ __forceinline__ void gld_lds16(const float* g, float* l) {
    __builtin_amdgcn_global_load_lds(
        (const __attribute__((address_space(1))) void*)g,
        (__attribute__((address_space(3))) void*)l,
        16, 0, 0);
}

// =====================================================================
// GEMM1: h[16384x512] = relu(feats[16384x1024] @ w_bneck[1024x512] + b)
// fp32 vector GEMM (fp32 REQUIRED: NMS ordering sensitive to ~1e-6 score
// gaps; bf16/MFMA noise would reorder proposals -> absmax ~0.5).
// 4x8 microtile (32 acc VGPRs), unroll 4, 64x128 block tile, BK=16,
// double-buffered LDS, B via global_load_lds. (unchanged from R3)
// =====================================================================
__global__ __launch_bounds__(256)
__attribute__((amdgpu_waves_per_eu(2, 4)))
void gemm1_kernel(
    const float* __restrict__ A, const float* __restrict__ Bw,
    const float* __restrict__ bias, float* __restrict__ C)
{
    __shared__ float As[2][16][68];    // [buf][k][m] transposed, padded
    __shared__ float Bs[2][16][128];   // [buf][k][n]  (no pad: load_lds linear)

    const int t  = threadIdx.x;
    const int m0 = blockIdx.x * 64;
    const int n0 = blockIdx.y * 128;
    const int tx = t & 15;             // n-dir: cols tx*4 and 64+tx*4
    const int ty = t >> 4;             // m-dir: rows ty*4 .. ty*4+3

    const int ar0 = t >> 2;            // A row in tile (0..63)
    const int ac0 = (t & 3) * 4;       // A col in tile (k)

    const float* asrc = A + (size_t)(m0 + ar0) * CIN + ac0;
    const float* bsrc = Bw + (size_t)(t >> 5) * CMID + n0 + (t & 31) * 4;
    float* bdst0 = &Bs[0][0][0] + t * 4;   // byte off = 16*t (lane-linear)
    float* bdst1 = &Bs[1][0][0] + t * 4;

    float4 c0a{0,0,0,0}, c0b{0,0,0,0}, c1a{0,0,0,0}, c1b{0,0,0,0};
    float4 c2a{0,0,0,0}, c2b{0,0,0,0}, c3a{0,0,0,0}, c3b{0,0,0,0};

    gld_lds16(bsrc, bdst0);
    gld_lds16(bsrc + 8 * CMID, bdst0 + 1024);
    float4 pa = *(const float4*)(asrc);
    As[0][ac0 + 0][ar0] = pa.x; As[0][ac0 + 1][ar0] = pa.y;
    As[0][ac0 + 2][ar0] = pa.z; As[0][ac0 + 3][ar0] = pa.w;
    __syncthreads();

#define FMA4(acc, s, b) { acc.x += (s)*(b).x; acc.y += (s)*(b).y; \
                          acc.z += (s)*(b).z; acc.w += (s)*(b).w; }

    for (int kt = 0; kt < 64; ++kt) {
        const int cur = kt & 1, nxt = cur ^ 1;
        if (kt < 63) {
            const int k0 = (kt + 1) * 16;
            float* bd = nxt ? bdst1 : bdst0;
            gld_lds16(bsrc + (size_t)k0 * CMID, bd);
            gld_lds16(bsrc + (size_t)(k0 + 8) * CMID, bd + 1024);
            pa = *(const float4*)(asrc + k0);
        }
#pragma unroll 4
        for (int kk = 0; kk < 16; ++kk) {
            float4 a  = *(const float4*)&As[cur][kk][ty * 4];
            float4 b0 = *(const float4*)&Bs[cur][kk][tx * 4];
            float4 b1 = *(const float4*)&Bs[cur][kk][64 + tx * 4];
            FMA4(c0a, a.x, b0) FMA4(c0b, a.x, b1)
            FMA4(c1a, a.y, b0) FMA4(c1b, a.y, b1)
            FMA4(c2a, a.z, b0) FMA4(c2b, a.z, b1)
            FMA4(c3a, a.w, b0) FMA4(c3b, a.w, b1)
        }
        if (kt < 63) {
            As[nxt][ac0 + 0][ar0] = pa.x; As[nxt][ac0 + 1][ar0] = pa.y;
            As[nxt][ac0 + 2][ar0] = pa.z; As[nxt][ac0 + 3][ar0] = pa.w;
        }
        __syncthreads();
    }
#undef FMA4

    const float4 bias0 = *(const float4*)(bias + n0 + tx * 4);
    const float4 bias1 = *(const float4*)(bias + n0 + 64 + tx * 4);
#define STROW(row, ca, cb) { \
    float4 o; \
    o.x = fmaxf(ca.x + bias0.x, 0.f); o.y = fmaxf(ca.y + bias0.y, 0.f); \
    o.z = fmaxf(ca.z + bias0.z, 0.f); o.w = fmaxf(ca.w + bias0.w, 0.f); \
    *(float4*)(C + (size_t)(row) * CMID + n0 + tx * 4) = o; \
    o.x = fmaxf(cb.x + bias1.x, 0.f); o.y = fmaxf(cb.y + bias1.y, 0.f); \
    o.z = fmaxf(cb.z + bias1.z, 0.f); o.w = fmaxf(cb.w + bias1.w, 0.f); \
    *(float4*)(C + (size_t)(row) * CMID + n0 + 64 + tx * 4) = o; }

    const int mr = m0 + ty * 4;
    STROW(mr + 0, c0a, c0b)
    STROW(mr + 1, c1a, c1b)
    STROW(mr + 2, c2a, c2b)
    STROW(mr + 3, c3a, c3b)
#undef STROW
}

// =====================================================================
// GEMM2: logits[16384 x 48(45 used)] = h[16384x512] @ [w_cls | w_reg]
// =====================================================================
__global__ __launch_bounds__(256) void gemm2_kernel(
    const float* __restrict__ h,
    const float* __restrict__ wcls, const float* __restrict__ bcls,
    const float* __restrict__ wreg, const float* __restrict__ breg,
    float* __restrict__ logits)
{
    __shared__ float hS[32][33];   // padded
    __shared__ float wS[32][48];

    const int t  = threadIdx.x;
    const int p0 = blockIdx.x * 32;
    const int px = t & 31;
    const int og = t >> 5;          // 0..7 -> outs og*6 .. og*6+5

    float acc[6] = {0.f, 0.f, 0.f, 0.f, 0.f, 0.f};

    for (int kt = 0; kt < 16; ++kt) {
        const int k0 = kt * 32;
        {   // stage h tile 32x32 (1 float4 per thread)
            int r = t >> 3, c4 = (t & 7) * 4;
            float4 v = *(const float4*)(h + (size_t)(p0 + r) * CMID + k0 + c4);
            hS[r][c4 + 0] = v.x; hS[r][c4 + 1] = v.y;
            hS[r][c4 + 2] = v.z; hS[r][c4 + 3] = v.w;
        }
#pragma unroll
        for (int i = 0; i < 6; ++i) {   // stage weights 32x48
            int idx = t + i * 256;
            int kk = idx / 48, o = idx - kk * 48;
            float val = 0.f;
            if (o < 9)       val = wcls[(size_t)(k0 + kk) * 9 + o];
            else if (o < 45) val = wreg[(size_t)(k0 + kk) * 36 + (o - 9)];
            wS[kk][o] = val;
        }
        __syncthreads();
#pragma unroll 8
        for (int kk = 0; kk < 32; ++kk) {
            float hv = hS[px][kk];
            const float* wr = &wS[kk][og * 6];
            acc[0] += hv * wr[0]; acc[1] += hv * wr[1]; acc[2] += hv * wr[2];
            acc[3] += hv * wr[3]; acc[4] += hv * wr[4]; acc[5] += hv * wr[5];
        }
        __syncthreads();
    }
#pragma unroll
    for (int c = 0; c < 6; ++c) {
        int o = og * 6 + c;
        if (o < 45) {
            float bv = (o < 9) ? bcls[o] : breg[o - 9];
            logits[(size_t)(p0 + px) * 48 + o] = acc[c] + bv;
        }
    }
}

// =====================================================================
// Decode: sigmoid -> cls_pred out; raw reg -> reg_pred out; box decode
// (clip [0,1]) -> boxes ws; histogram of score upper-16 float bits.
// R5 fix: scores cluster in (0.44,0.56) (~47 distinct upper-16 bins) ->
// single-copy global atomics serialized at ~6cyc/op = 370us. Now 64
// histogram copies (block b -> copy b&63): per-copy load 2304 adds.
// =====================================================================
__global__ __launch_bounds__(256) void decode_kernel(
    const float* __restrict__ logits, const float4* __restrict__ ancs,
    float* __restrict__ out, float4* __restrict__ boxes,
    unsigned int* __restrict__ histN)
{
    int i = blockIdx.x * 256 + threadIdx.x;     // < 147456
    int p = i / 9, a = i - p * 9;
    const float* lrow = logits + (size_t)p * 48;
    float lg = lrow[a];
    float score = 1.f / (1.f + expf(-lg));
    out[CLS_OFF + i] = score;

    float r0 = lrow[9 + a * 4 + 0];
    float r1 = lrow[9 + a * 4 + 1];
    float r2 = lrow[9 + a * 4 + 2];
    float r3 = lrow[9 + a * 4 + 3];
    float4 rg; rg.x = r0; rg.y = r1; rg.z = r2; rg.w = r3;
    *(float4*)(out + REG_OFF + (size_t)i * 4) = rg;

    float4 an = ancs[i];
    float cx = an.x + r0 * an.z;
    float cy = an.y + r1 * an.w;
    float ww = an.z * expf(r2);
    float hh = an.w * expf(r3);
    float4 bb;
    bb.x = fminf(fmaxf(cx - ww * 0.5f, 0.f), 1.f);
    bb.y = fminf(fmaxf(cy - hh * 0.5f, 0.f), 1.f);
    bb.z = fminf(fmaxf(cx + ww * 0.5f, 0.f), 1.f);
    bb.w = fminf(fmaxf(cy + hh * 0.5f, 0.f), 1.f);
    boxes[i] = bb;

    unsigned int sb = __float_as_uint(score);   // positive -> bit-monotone
    atomicAdd(&histN[(unsigned)(blockIdx.x & (NHCOPY - 1)) * 65536u + (sb >> 16)], 1u);
}

// =====================================================================
// Histogram reduce: hist[b] = sum over 64 copies. 256 blocks x 256 thr,
// one bin per thread; reads coalesced across threads within a copy.
// =====================================================================
__global__ __launch_bounds__(256) void hreduce_kernel(
    const unsigned int* __restrict__ histN, unsigned int* __restrict__ hist)
{
    int b = blockIdx.x * 256 + threadIdx.x;    // < 65536
    unsigned int s = 0;
#pragma unroll 8
    for (int c = 0; c < NHCOPY; ++c) s += histN[(unsigned)c * 65536u + b];
    hist[b] = s;
}

// =====================================================================
// Scan: find threshold bin T = max bin with cum(>=T) >= PRE_NMS.
// =====================================================================
__global__ __launch_bounds__(256) void scan_kernel(
    const unsigned int* __restrict__ hist, unsigned int* __restrict__ meta)
{
    __shared__ unsigned int sums[256];
    __shared__ unsigned int sc[256];
    __shared__ unsigned int sc2[256];
    __shared__ int cstar;
    __shared__ unsigned int saShared;
    __shared__ int tbin;

    int t = threadIdx.x;
    if (t == 0) tbin = -1;

    unsigned int s = 0;
    int base = t << 8;
    for (int b = 0; b < 256; b += 4) {
        uint4 v = *(const uint4*)(hist + base + b);
        s += v.x + v.y + v.z + v.w;
    }
    sums[t] = s;
    __syncthreads();

    sc[t] = sums[255 - t];
    __syncthreads();
    for (int off = 1; off < 256; off <<= 1) {
        unsigned int v = sc[t];
        unsigned int add = (t >= off) ? sc[t - off] : 0u;
        __syncthreads();
        sc[t] = v + add;
        __syncthreads();
    }
    {
        unsigned int sa = (t == 255) ? 0u : sc[254 - t];
        if (sa < PRE_NMS && sa + sums[t] >= PRE_NMS) { cstar = t; saShared = sa; }
    }
    __syncthreads();

    int c = cstar;
    unsigned int SA = saShared;
    sc2[t] = hist[c * 256 + 255 - t];
    __syncthreads();
    for (int off = 1; off < 256; off <<= 1) {
        unsigned int v = sc2[t];
        unsigned int add = (t >= off) ? sc2[t - off] : 0u;
        __syncthreads();
        sc2[t] = v + add;
        __syncthreads();
    }
    {
        unsigned int si = sc2[255 - t];
        int cand = (SA + si >= PRE_NMS) ? t : -1;
        atomicMax(&tbin, cand);
    }
    __syncthreads();
    if (t == 0) meta[1] = (unsigned int)(c * 256 + tbin);
}

// =====================================================================
// Collect: all anchors with score bin >= T -> composite sort keys.
// key = score_bits<<32 | (0xFFFFFFFF - idx): descending == stable
// argsort(-score) with index tie-break (matches jnp.argsort).
// =====================================================================
__global__ __launch_bounds__(256) void collect_kernel(
    const float* __restrict__ scores, const unsigned int* __restrict__ meta,
    unsigned long long* __restrict__ coll, unsigned int* __restrict__ cnt)
{
    int i = blockIdx.x * 256 + threadIdx.x;
    unsigned int T = meta[1];
    unsigned int sb = __float_as_uint(scores[i]);
    if ((sb >> 16) >= T) {
        unsigned int pos = atomicAdd(cnt, 1u);
        if (pos < CAP_COLL)
            coll[pos] = ((unsigned long long)sb << 32) |
                        (unsigned long long)(0xFFFFFFFFu - (unsigned int)i);
    }
}

// =====================================================================
// Sort: single-block bitonic sort (descending) of up to 8192 keys in LDS
// (64KB), then gather top-6000 boxes in sorted order.
// =====================================================================
__global__ __launch_bounds__(1024) void sort_kernel(
    const unsigned long long* __restrict__ coll,
    const unsigned int* __restrict__ cnt,
    const float4* __restrict__ boxes, float4* __restrict__ sboxes)
{
    __shared__ unsigned long long keys[8192];   // 64 KB
    int t = threadIdx.x;
    unsigned int n = cnt[0];
    if (n > CAP_COLL) n = CAP_COLL;
    for (int j = t; j < 8192; j += 1024)
        keys[j] = (j < (int)n) ? coll[j] : 0ULL;
    __syncthreads();

    for (int k = 2; k <= 8192; k <<= 1) {
        for (int j = k >> 1; j > 0; j >>= 1) {
            for (int u = t; u < 4096; u += 1024) {
                int i1 = ((u & ~(j - 1)) << 1) | (u & (j - 1));
                int i2 = i1 | j;
                unsigned long long a = keys[i1], b = keys[i2];
                bool up = (i1 & k) == 0;
                bool sw = up ? (a < b) : (a > b);   // descending
                if (sw) { keys[i1] = b; keys[i2] = a; }
            }
            __syncthreads();
        }
    }
    for (int j = t; j < PRE_NMS; j += 1024) {
        unsigned int idx = 0xFFFFFFFFu - (unsigned int)(keys[j] & 0xFFFFFFFFULL);
        if (idx > NANC - 1) idx = NANC - 1;   // safety clamp
        sboxes[j] = boxes[idx];
    }
}

// =====================================================================
// NMS matrix build (torchvision-style): strict-upper suppression bitmask.
// mask[r][cb] bit i set  <=>  j = cb*64+i, j > r, IoU(r,j) > 0.7.
// Strict-upper == reference's bidirectional suppression because the
// selection order is increasing index (boxes sorted by score).
// =====================================================================
__global__ __launch_bounds__(64) void nmsmat_kernel(
    const float4* __restrict__ sboxes, unsigned long long* __restrict__ mask)
{
    const int rb = blockIdx.x, cb = blockIdx.y;
    if (cb < rb) return;
    __shared__ float cx1[64], cy1[64], cx2[64], cy2[64], car[64];

    const int t = threadIdx.x;
    const int c = cb * 64 + t;
    float4 b = (c < PRE_NMS) ? sboxes[c] : make_float4(0.f, 0.f, 0.f, 0.f);
    cx1[t] = b.x; cy1[t] = b.y; cx2[t] = b.z; cy2[t] = b.w;
    car[t] = (b.z - b.x) * (b.w - b.y);
    __syncthreads();

    const int r = rb * 64 + t;
    if (r >= PRE_NMS) return;
    const float4 rbx = sboxes[r];
    const float ra = (rbx.z - rbx.x) * (rbx.w - rbx.y);

    unsigned long long w = 0ULL;
#pragma unroll 8
    for (int i = 0; i < 64; ++i) {
        int j = cb * 64 + i;
        float iw = fmaxf(fminf(rbx.z, cx2[i]) - fmaxf(rbx.x, cx1[i]), 0.f);
        float ih = fmaxf(fminf(rbx.w, cy2[i]) - fmaxf(rbx.y, cy1[i]), 0.f);
        float inter = iw * ih;
        float uni = ra + car[i] - inter;
        float iou = (uni > 0.f) ? (inter / uni) : 0.f;   // dummy j>=6000 -> 0
        if (iou > IOU_THR && j > r) w |= (1ULL << i);
    }
    mask[(size_t)r * NWORDS + cb] = w;
}

// =====================================================================
// NMS resolve: ONE wave, no barriers, valid bitmask in REGISTERS
// (lane t owns words 2t and 2t+1). Per selection: ballot+ctz+shfl finds
// min surviving index, one predicated global row load ANDs out
// suppressed bits. NB __ballot arg must be a bool-ized compare (int
// param truncates u64 -> R4 bug).
// =====================================================================
__global__ __launch_bounds__(64) void nmsresolve_kernel(
    const float4* __restrict__ sboxes,
    const unsigned long long* __restrict__ mask,
    float* __restrict__ prop)
{
    const int t = threadIdx.x;      // one wave
    for (int j = t; j < POST_NMS * 4; j += 64) prop[j] = 0.f;

    const int w0 = 2 * t, w1 = 2 * t + 1;
    unsigned long long v0 = 0ULL, v1 = 0ULL;
    if (w0 < 93) v0 = ~0ULL; else if (w0 == 93) v0 = (1ULL << 48) - 1ULL;
    if (w1 < 93) v1 = ~0ULL; else if (w1 == 93) v1 = (1ULL << 48) - 1ULL;

    int cnt = 0;
    while (cnt < POST_NMS) {
        int c = 0x7fffffff;
        if (v0) c = (w0 << 6) + __builtin_ctzll(v0);
        else if (v1) c = (w1 << 6) + __builtin_ctzll(v1);
        unsigned long long bal = __ballot((v0 | v1) != 0ULL);
        if (!bal) break;
        int F = __builtin_ctzll(bal);
        int g = __shfl(c, F, 64);
        const int wg = g >> 6, bg = g & 63;

        if (t == 0) {
            float4 bb = sboxes[g];
            *(float4*)(prop + cnt * 4) = bb;
        }
        const unsigned long long* row = mask + (size_t)g * NWORDS;
        unsigned long long m0 = (w0 >= wg) ? row[w0] : 0ULL;
        unsigned long long m1 = (w1 >= wg) ? row[w1] : 0ULL;
        v0 &= ~m0; v1 &= ~m1;
        if (w0 == wg) v0 &= ~(1ULL << bg);
        if (w1 == wg) v1 &= ~(1ULL << bg);
        ++cnt;
    }
}

// =====================================================================
extern "C" void kernel_launch(void* const* d_in, const int* in_sizes, int n_in,
                              void* d_out, int out_size, void* d_ws, size_t ws_size,
                              hipStream_t stream)
{
    const float*  feats   = (const float*)d_in[0];
    const float4* ancs    = (const float4*)d_in[1];
    // d_in[2] = ancs_valid (unused by reference)
    const float*  w_bneck = (const float*)d_in[3];
    const float*  b_bneck = (const float*)d_in[4];
    const float*  w_cls   = (const float*)d_in[5];
    const float*  b_cls   = (const float*)d_in[6];
    const float*  w_reg   = (const float*)d_in[7];
    const float*  b_reg   = (const float*)d_in[8];

    float* out = (float*)d_out;
    char*  ws  = (char*)d_ws;
    float*              h      = (float*)(ws + WS_H);
    float*              logits = (float*)(ws + WS_LOGITS);
    float4*             boxes  = (float4*)(ws + WS_BOXES);
    unsigned int*       histN  = (unsigned int*)(ws + WS_HISTN); // aliases h
    unsigned int*       hist   = (unsigned int*)(ws + WS_HIST);
    unsigned int*       meta   = (unsigned int*)(ws + WS_META);
    unsigned long long* coll   = (unsigned long long*)(ws + WS_COLL);
    float4*             sboxes = (float4*)(ws + WS_SBOX);
    unsigned long long* mask   = (unsigned long long*)(ws + WS_MASK); // aliases h

    hipMemsetAsync(ws + WS_META, 0, 256, stream);

    gemm1_kernel<<<dim3(256, 4), 256, 0, stream>>>(feats, w_bneck, b_bneck, h);
    gemm2_kernel<<<512, 256, 0, stream>>>(h, w_cls, b_cls, w_reg, b_reg, logits);
    // histN region (aliases h) becomes dead only after gemm2 completes
    hipMemsetAsync(ws + WS_HISTN, 0, (size_t)NHCOPY * 65536 * 4, stream);
    decode_kernel<<<576, 256, 0, stream>>>(logits, ancs, out, boxes, histN);
    hreduce_kernel<<<256, 256, 0, stream>>>(histN, hist);
    scan_kernel<<<1, 256, 0, stream>>>(hist, meta);
    collect_kernel<<<576, 256, 0, stream>>>(out, meta, coll, &meta[0]);
    sort_kernel<<<1, 1024, 0, stream>>>(coll, meta, boxes, sboxes);
    nmsmat_kernel<<<dim3(94, 94), 64, 0, stream>>>(sboxes, mask);
    nmsresolve_kernel<<<1, 64, 0, stream>>>(sboxes, mask, out + PROP_OFF);
}

// Round 7
// 718.734 us; speedup vs baseline: 3.7792x; 1.0501x over previous
//
#include <hip/hip_runtime.h>
#include <cstdint>
#include <cstddef>

// ---------------- problem constants ----------------
#define P_TOT    16384      // B*H*W = 4*64*64
#define CIN      1024
#define CMID     512
#define NA       9
#define NANC     147456     // P_TOT * NA
#define PRE_NMS  6000
#define POST_NMS 300
#define IOU_THR  0.7f
#define NWORDS   94         // ceil(6000/64)
#define NHCOPY   64         // histogram copies (contention spreading)

// output layout (floats): cls_pred | reg_pred | proposals
#define CLS_OFF  0
#define REG_OFF  147456
#define PROP_OFF 737280

// ---------------- workspace layout (bytes) ----------------
// Aliasing into the dead h region (h: 33.5 MB, dead after gemm2):
//   WS_MASK  @ 0       (4.5 MB, written by nmsmat, after rank)
//   WS_HISTN @ 8 MB    (16 MB, 64 histogram copies, written by decode)
// WS_WCOMB aliases WS_HIST (wcomb dead after gemm2; hist written later
// by hreduce). Lifetimes verified stream-ordered. Total ws ~39.5 MB.
#define WS_H        0u          // 16384*512*4   = 33554432
#define WS_MASK     0u          // 6000*94*8     = 4512000   (aliases h)
#define WS_HISTN    8388608u    // 64*65536*4    = 16777216  (aliases h)
#define WS_LOGITS   33554432u   // 16384*48*4    = 3145728
#define WS_BOXES    36700160u   // 147456*4*4    = 2359296
#define WS_HIST     39059456u   // 65536*4       = 262144
#define WS_WCOMB    39059456u   // 512*48*4      = 98304     (aliases hist)
#define WS_META     39321600u   // 64*4          = 256   (meta[0]=cnt, meta[1]=T)
#define WS_COLL     39321856u   // 8192*8        = 65536
#define WS_SBOX     39387392u   // 6000*16       = 96000  -> end ~39.5 MB
#define CAP_COLL    8192

__device__ __forceinline__ int imin(int a, int b) { return a < b ? a : b; }

// async global->LDS, 16B per lane. LDS dest must be wave-uniform base +
// lane*16 -> per-lane pointer linear in thread id.
__device__ __forceinline__ void gld_lds16(const float* g, float* l) {
    __builtin_amdgcn_global_load_lds(
        (const __attribute__((address_space(1))) void*)g,
        (__attribute__((address_space(3))) void*)l,
        16, 0, 0);
}

// =====================================================================
// GEMM1: h[16384x512] = relu(feats[16384x1024] @ w_bneck[1024x512] + b)
// fp32 vector GEMM (fp32 REQUIRED: NMS ordering sensitive to ~1e-6 score
// gaps; bf16/MFMA noise would reorder proposals -> absmax ~0.5).
// R7: 128x128 tile, 8x8 microtile (64 acc in 16 NAMED float4), unroll 2
// (operand window ~32 regs; R2's full-unroll window ~256 was the spill
// cause). 64 FMA per 4 ds_read_b128. B via global_load_lds, dbuf LDS.
// Spill sentinel: WRITE_SIZE must stay 32768 KB.
// =====================================================================
__global__ __launch_bounds__(256) void gemm1_kernel(
    const float* __restrict__ A, const float* __restrict__ Bw,
    const float* __restrict__ bias, float* __restrict__ C)
{
    __shared__ float As[2][16][132];   // [buf][k][m] transposed, padded
    __shared__ float Bs[2][16][128];   // [buf][k][n]  (no pad: load_lds linear)

    const int t  = threadIdx.x;
    const int m0 = blockIdx.x * 128;
    const int n0 = blockIdx.y * 128;
    const int tx = t & 15;             // n-dir: cols tx*4, 64+tx*4
    const int ty = t >> 4;             // m-dir: rows ty*4..+3, 64+ty*4..+3

    const int ar0 = t >> 2;            // A row in tile (0..63), second +64
    const int ac0 = (t & 3) * 4;       // A col in tile (k)

    const float* asrc0 = A + (size_t)(m0 + ar0) * CIN + ac0;
    const float* asrc1 = asrc0 + (size_t)64 * CIN;
    const float* bsrc  = Bw + (size_t)(t >> 5) * CMID + n0 + (t & 31) * 4;
    float* bdst0 = &Bs[0][0][0] + t * 4;   // byte off = 16*t (lane-linear)
    float* bdst1 = &Bs[1][0][0] + t * 4;

    float4 c0a{0,0,0,0}, c0b{0,0,0,0}, c1a{0,0,0,0}, c1b{0,0,0,0};
    float4 c2a{0,0,0,0}, c2b{0,0,0,0}, c3a{0,0,0,0}, c3b{0,0,0,0};
    float4 c4a{0,0,0,0}, c4b{0,0,0,0}, c5a{0,0,0,0}, c5b{0,0,0,0};
    float4 c6a{0,0,0,0}, c6b{0,0,0,0}, c7a{0,0,0,0}, c7b{0,0,0,0};

    // ---- prologue: tile 0 into buf 0 ----
    gld_lds16(bsrc, bdst0);
    gld_lds16(bsrc + 8 * CMID, bdst0 + 1024);
    float4 pa0 = *(const float4*)(asrc0);
    float4 pa1 = *(const float4*)(asrc1);
    As[0][ac0 + 0][ar0] = pa0.x; As[0][ac0 + 1][ar0] = pa0.y;
    As[0][ac0 + 2][ar0] = pa0.z; As[0][ac0 + 3][ar0] = pa0.w;
    As[0][ac0 + 0][ar0 + 64] = pa1.x; As[0][ac0 + 1][ar0 + 64] = pa1.y;
    As[0][ac0 + 2][ar0 + 64] = pa1.z; As[0][ac0 + 3][ar0 + 64] = pa1.w;
    __syncthreads();

#define FMA4(acc, s, b) { acc.x += (s)*(b).x; acc.y += (s)*(b).y; \
                          acc.z += (s)*(b).z; acc.w += (s)*(b).w; }

    for (int kt = 0; kt < 64; ++kt) {
        const int cur = kt & 1, nxt = cur ^ 1;
        if (kt < 63) {
            const int k0 = (kt + 1) * 16;
            float* bd = nxt ? bdst1 : bdst0;
            gld_lds16(bsrc + (size_t)k0 * CMID, bd);
            gld_lds16(bsrc + (size_t)(k0 + 8) * CMID, bd + 1024);
            pa0 = *(const float4*)(asrc0 + k0);
            pa1 = *(const float4*)(asrc1 + k0);
        }
#pragma unroll 2
        for (int kk = 0; kk < 16; ++kk) {
            float4 a0 = *(const float4*)&As[cur][kk][ty * 4];
            float4 a1 = *(const float4*)&As[cur][kk][64 + ty * 4];
            float4 b0 = *(const float4*)&Bs[cur][kk][tx * 4];
            float4 b1 = *(const float4*)&Bs[cur][kk][64 + tx * 4];
            FMA4(c0a, a0.x, b0) FMA4(c0b, a0.x, b1)
            FMA4(c1a, a0.y, b0) FMA4(c1b, a0.y, b1)
            FMA4(c2a, a0.z, b0) FMA4(c2b, a0.z, b1)
            FMA4(c3a, a0.w, b0) FMA4(c3b, a0.w, b1)
            FMA4(c4a, a1.x, b0) FMA4(c4b, a1.x, b1)
            FMA4(c5a, a1.y, b0) FMA4(c5b, a1.y, b1)
            FMA4(c6a, a1.z, b0) FMA4(c6b, a1.z, b1)
            FMA4(c7a, a1.w, b0) FMA4(c7b, a1.w, b1)
        }
        if (kt < 63) {
            As[nxt][ac0 + 0][ar0] = pa0.x; As[nxt][ac0 + 1][ar0] = pa0.y;
            As[nxt][ac0 + 2][ar0] = pa0.z; As[nxt][ac0 + 3][ar0] = pa0.w;
            As[nxt][ac0 + 0][ar0 + 64] = pa1.x; As[nxt][ac0 + 1][ar0 + 64] = pa1.y;
            As[nxt][ac0 + 2][ar0 + 64] = pa1.z; As[nxt][ac0 + 3][ar0 + 64] = pa1.w;
        }
        __syncthreads();
    }
#undef FMA4

    const float4 bias0 = *(const float4*)(bias + n0 + tx * 4);
    const float4 bias1 = *(const float4*)(bias + n0 + 64 + tx * 4);
#define STROW(row, ca, cb) { \
    float4 o; \
    o.x = fmaxf(ca.x + bias0.x, 0.f); o.y = fmaxf(ca.y + bias0.y, 0.f); \
    o.z = fmaxf(ca.z + bias0.z, 0.f); o.w = fmaxf(ca.w + bias0.w, 0.f); \
    *(float4*)(C + (size_t)(row) * CMID + n0 + tx * 4) = o; \
    o.x = fmaxf(cb.x + bias1.x, 0.f); o.y = fmaxf(cb.y + bias1.y, 0.f); \
    o.z = fmaxf(cb.z + bias1.z, 0.f); o.w = fmaxf(cb.w + bias1.w, 0.f); \
    *(float4*)(C + (size_t)(row) * CMID + n0 + 64 + tx * 4) = o; }

    const int mr = m0 + ty * 4;
    STROW(mr + 0, c0a, c0b)   STROW(mr + 1, c1a, c1b)
    STROW(mr + 2, c2a, c2b)   STROW(mr + 3, c3a, c3b)
    STROW(mr + 64, c4a, c4b)  STROW(mr + 65, c5a, c5b)
    STROW(mr + 66, c6a, c6b)  STROW(mr + 67, c7a, c7b)
#undef STROW
}

// =====================================================================
// wprep: combined weight matrix wcomb[512][48]: cols 0..8 = w_cls,
// 9..44 = w_reg, 45..47 = 0. One-time; removes div-48 + strided scalar
// loads from gemm2's per-block staging (R6 did it 512x16 times).
// =====================================================================
__global__ __launch_bounds__(256) void wprep_kernel(
    const float* __restrict__ wcls, const float* __restrict__ wreg,
    float* __restrict__ wcomb)
{
    int i = blockIdx.x * 256 + threadIdx.x;    // < 24576
    int k = i / 48, o = i - k * 48;
    float v = 0.f;
    if (o < 9)       v = wcls[k * 9 + o];
    else if (o < 45) v = wreg[k * 36 + (o - 9)];
    wcomb[i] = v;
}

// =====================================================================
// GEMM2 v2: logits[16384 x 48(45)] = h @ wcomb. 64 px/block, 256 blocks,
// 12 outs/thread (px = t&63, og = t>>6). Per kk: 1 hS read (2-way-free
// conflict) + 3 wS float4 broadcasts + 12 FMA.
// =====================================================================
__global__ __launch_bounds__(256) void gemm2_kernel(
    const float* __restrict__ h, const float* __restrict__ wcomb,
    const float* __restrict__ bcls, const float* __restrict__ breg,
    float* __restrict__ logits)
{
    __shared__ float hS[64][33];   // padded
    __shared__ float wS[32][48];

    const int t  = threadIdx.x;
    const int p0 = blockIdx.x * 64;
    const int px = t & 63;
    const int og = t >> 6;          // 0..3 -> outs og*12 .. og*12+11

    const int hr = t >> 2;          // stage row 0..63
    const int hc = (t & 3) * 4;     // stage col

    float acc[12] = {};

    for (int kt = 0; kt < 16; ++kt) {
        const int k0 = kt * 32;
        {   // stage h tile 64x32 (2 float4/thread)
            const float* hp = h + (size_t)(p0 + hr) * CMID + k0 + hc;
            float4 v0 = *(const float4*)(hp);
            float4 v1 = *(const float4*)(hp + 16);
            hS[hr][hc + 0] = v0.x; hS[hr][hc + 1] = v0.y;
            hS[hr][hc + 2] = v0.z; hS[hr][hc + 3] = v0.w;
            hS[hr][16 + hc + 0] = v1.x; hS[hr][16 + hc + 1] = v1.y;
            hS[hr][16 + hc + 2] = v1.z; hS[hr][16 + hc + 3] = v1.w;
        }
        {   // stage w tile 32x48 = 384 float4
            int idx = t;
            if (idx < 384) {
                int kk = idx / 12, o4 = (idx - kk * 12) * 4;
                *(float4*)&wS[kk][o4] = *(const float4*)&wcomb[(size_t)(k0 + kk) * 48 + o4];
            }
            idx = t + 256;
            if (idx < 384) {
                int kk = idx / 12, o4 = (idx - kk * 12) * 4;
                *(float4*)&wS[kk][o4] = *(const float4*)&wcomb[(size_t)(k0 + kk) * 48 + o4];
            }
        }
        __syncthreads();
#pragma unroll 4
        for (int kk = 0; kk < 32; ++kk) {
            float hv = hS[px][kk];
            float4 w0 = *(const float4*)&wS[kk][og * 12];
            float4 w1 = *(const float4*)&wS[kk][og * 12 + 4];
            float4 w2 = *(const float4*)&wS[kk][og * 12 + 8];
            acc[0] += hv * w0.x; acc[1]  += hv * w0.y; acc[2]  += hv * w0.z; acc[3]  += hv * w0.w;
            acc[4] += hv * w1.x; acc[5]  += hv * w1.y; acc[6]  += hv * w1.z; acc[7]  += hv * w1.w;
            acc[8] += hv * w2.x; acc[9]  += hv * w2.y; acc[10] += hv * w2.z; acc[11] += hv * w2.w;
        }
        __syncthreads();
    }
#pragma unroll
    for (int c = 0; c < 12; ++c) {
        int o = og * 12 + c;
        if (o < 45) {
            float bv = (o < 9) ? bcls[o] : breg[o - 9];
            logits[(size_t)(p0 + px) * 48 + o] = acc[c] + bv;
        }
    }
}

// =====================================================================
// Decode: sigmoid -> cls_pred out; raw reg -> reg_pred out; box decode
// (clip [0,1]) -> boxes ws; 64-copy histogram of score upper-16 bits
// (R5: single-copy atomics on ~47 hot bins serialized to 370us).
// =====================================================================
__global__ __launch_bounds__(256) void decode_kernel(
    const float* __restrict__ logits, const float4* __restrict__ ancs,
    float* __restrict__ out, float4* __restrict__ boxes,
    unsigned int* __restrict__ histN)
{
    int i = blockIdx.x * 256 + threadIdx.x;     // < 147456
    int p = i / 9, a = i - p * 9;
    const float* lrow = logits + (size_t)p * 48;
    float lg = lrow[a];
    float score = 1.f / (1.f + expf(-lg));
    out[CLS_OFF + i] = score;

    float r0 = lrow[9 + a * 4 + 0];
    float r1 = lrow[9 + a * 4 + 1];
    float r2 = lrow[9 + a * 4 + 2];
    float r3 = lrow[9 + a * 4 + 3];
    float4 rg; rg.x = r0; rg.y = r1; rg.z = r2; rg.w = r3;
    *(float4*)(out + REG_OFF + (size_t)i * 4) = rg;

    float4 an = ancs[i];
    float cx = an.x + r0 * an.z;
    float cy = an.y + r1 * an.w;
    float ww = an.z * expf(r2);
    float hh = an.w * expf(r3);
    float4 bb;
    bb.x = fminf(fmaxf(cx - ww * 0.5f, 0.f), 1.f);
    bb.y = fminf(fmaxf(cy - hh * 0.5f, 0.f), 1.f);
    bb.z = fminf(fmaxf(cx + ww * 0.5f, 0.f), 1.f);
    bb.w = fminf(fmaxf(cy + hh * 0.5f, 0.f), 1.f);
    boxes[i] = bb;

    unsigned int sb = __float_as_uint(score);   // positive -> bit-monotone
    atomicAdd(&histN[(unsigned)(blockIdx.x & (NHCOPY - 1)) * 65536u + (sb >> 16)], 1u);
}

// =====================================================================
// Histogram reduce: hist[b] = sum over 64 copies.
// =====================================================================
__global__ __launch_bounds__(256) void hreduce_kernel(
    const unsigned int* __restrict__ histN, unsigned int* __restrict__ hist)
{
    int b = blockIdx.x * 256 + threadIdx.x;    // < 65536
    unsigned int s = 0;
#pragma unroll 8
    for (int c = 0; c < NHCOPY; ++c) s += histN[(unsigned)c * 65536u + b];
    hist[b] = s;
}

// =====================================================================
// Scan: find threshold bin T = max bin with cum(>=T) >= PRE_NMS.
// =====================================================================
__global__ __launch_bounds__(256) void scan_kernel(
    const unsigned int* __restrict__ hist, unsigned int* __restrict__ meta)
{
    __shared__ unsigned int sums[256];
    __shared__ unsigned int sc[256];
    __shared__ unsigned int sc2[256];
    __shared__ int cstar;
    __shared__ unsigned int saShared;
    __shared__ int tbin;

    int t = threadIdx.x;
    if (t == 0) tbin = -1;

    unsigned int s = 0;
    int base = t << 8;
    for (int b = 0; b < 256; b += 4) {
        uint4 v = *(const uint4*)(hist + base + b);
        s += v.x + v.y + v.z + v.w;
    }
    sums[t] = s;
    __syncthreads();

    sc[t] = sums[255 - t];
    __syncthreads();
    for (int off = 1; off < 256; off <<= 1) {
        unsigned int v = sc[t];
        unsigned int add = (t >= off) ? sc[t - off] : 0u;
        __syncthreads();
        sc[t] = v + add;
        __syncthreads();
    }
    {
        unsigned int sa = (t == 255) ? 0u : sc[254 - t];
        if (sa < PRE_NMS && sa + sums[t] >= PRE_NMS) { cstar = t; saShared = sa; }
    }
    __syncthreads();

    int c = cstar;
    unsigned int SA = saShared;
    sc2[t] = hist[c * 256 + 255 - t];
    __syncthreads();
    for (int off = 1; off < 256; off <<= 1) {
        unsigned int v = sc2[t];
        unsigned int add = (t >= off) ? sc2[t - off] : 0u;
        __syncthreads();
        sc2[t] = v + add;
        __syncthreads();
    }
    {
        unsigned int si = sc2[255 - t];
        int cand = (SA + si >= PRE_NMS) ? t : -1;
        atomicMax(&tbin, cand);
    }
    __syncthreads();
    if (t == 0) meta[1] = (unsigned int)(c * 256 + tbin);
}

// =====================================================================
// Collect: all anchors with score bin >= T -> composite sort keys.
// key = score_bits<<32 | (0xFFFFFFFF - idx): larger == (higher score,
// then lower idx) -> matches stable argsort(-score).
// =====================================================================
__global__ __launch_bounds__(256) void collect_kernel(
    const float* __restrict__ scores, const unsigned int* __restrict__ meta,
    unsigned long long* __restrict__ coll, unsigned int* __restrict__ cnt)
{
    int i = blockIdx.x * 256 + threadIdx.x;
    unsigned int T = meta[1];
    unsigned int sb = __float_as_uint(scores[i]);
    if ((sb >> 16) >= T) {
        unsigned int pos = atomicAdd(cnt, 1u);
        if (pos < CAP_COLL)
            coll[pos] = ((unsigned long long)sb << 32) |
                        (unsigned long long)(0xFFFFFFFFu - (unsigned int)i);
    }
}

// =====================================================================
// Rank (replaces R6's single-block bitonic, ~50us -> ~8us): keys are
// UNIQUE (idx tiebreak), so rank(k) = #{keys > k} is an exact
// permutation; scatter box straight to its sorted slot. O(n^2)=67M
// compares but embarrassingly parallel (32 blocks). Order-independent
// of collect's nondeterministic append order.
// =====================================================================
__global__ __launch_bounds__(256) void rank_kernel(
    const unsigned long long* __restrict__ coll,
    const unsigned int* __restrict__ cnt,
    const float4* __restrict__ boxes, float4* __restrict__ sboxes)
{
    __shared__ unsigned long long ks[1024];
    const int t = threadIdx.x;
    const int gid = blockIdx.x * 256 + t;
    unsigned int n = cnt[0];
    if (n > CAP_COLL) n = CAP_COLL;
    unsigned long long me = (gid < (int)n) ? coll[gid] : 0ULL;
    int rank = 0;
    for (int base = 0; base < CAP_COLL; base += 1024) {
#pragma unroll
        for (int i = 0; i < 4; ++i) {
            int j = base + i * 256 + t;
            ks[i * 256 + t] = (j < (int)n) ? coll[j] : 0ULL;
        }
        __syncthreads();
#pragma unroll 8
        for (int j = 0; j < 1024; j += 2) {
            rank += (ks[j] > me) + (ks[j + 1] > me);
        }
        __syncthreads();
    }
    if (gid < (int)n && rank < PRE_NMS) {
        unsigned int idx = 0xFFFFFFFFu - (unsigned int)(me & 0xFFFFFFFFULL);
        if (idx > NANC - 1) idx = NANC - 1;   // safety clamp
        sboxes[rank] = boxes[idx];
    }
}

// =====================================================================
// NMS matrix build: strict-upper suppression bitmask.
// mask[r][cb] bit i set <=> j = cb*64+i, j > r, IoU(r,j) > 0.7.
// =====================================================================
__global__ __launch_bounds__(64) void nmsmat_kernel(
    const float4* __restrict__ sboxes, unsigned long long* __restrict__ mask)
{
    const int rb = blockIdx.x, cb = blockIdx.y;
    if (cb < rb) return;
    __shared__ float cx1[64], cy1[64], cx2[64], cy2[64], car[64];

    const int t = threadIdx.x;
    const int c = cb * 64 + t;
    float4 b = (c < PRE_NMS) ? sboxes[c] : make_float4(0.f, 0.f, 0.f, 0.f);
    cx1[t] = b.x; cy1[t] = b.y; cx2[t] = b.z; cy2[t] = b.w;
    car[t] = (b.z - b.x) * (b.w - b.y);
    __syncthreads();

    const int r = rb * 64 + t;
    if (r >= PRE_NMS) return;
    const float4 rbx = sboxes[r];
    const float ra = (rbx.z - rbx.x) * (rbx.w - rbx.y);

    unsigned long long w = 0ULL;
#pragma unroll 8
    for (int i = 0; i < 64; ++i) {
        int j = cb * 64 + i;
        float iw = fmaxf(fminf(rbx.z, cx2[i]) - fmaxf(rbx.x, cx1[i]), 0.f);
        float ih = fmaxf(fminf(rbx.w, cy2[i]) - fmaxf(rbx.y, cy1[i]), 0.f);
        float inter = iw * ih;
        float uni = ra + car[i] - inter;
        float iou = (uni > 0.f) ? (inter / uni) : 0.f;   // dummy j>=6000 -> 0
        if (iou > IOU_THR && j > r) w |= (1ULL << i);
    }
    mask[(size_t)r * NWORDS + cb] = w;
}

// =====================================================================
// NMS resolve: ONE wave, valid bitmask in registers (lane t owns words
// 2t, 2t+1). __ballot arg must be a bool-ized compare (R4 truncation).
// =====================================================================
__global__ __launch_bounds__(64) void nmsresolve_kernel(
    const float4* __restrict__ sboxes,
    const unsigned long long* __restrict__ mask,
    float* __restrict__ prop)
{
    const int t = threadIdx.x;      // one wave
    for (int j = t; j < POST_NMS * 4; j += 64) prop[j] = 0.f;

    const int w0 = 2 * t, w1 = 2 * t + 1;
    unsigned long long v0 = 0ULL, v1 = 0ULL;
    if (w0 < 93) v0 = ~0ULL; else if (w0 == 93) v0 = (1ULL << 48) - 1ULL;
    if (w1 < 93) v1 = ~0ULL; else if (w1 == 93) v1 = (1ULL << 48) - 1ULL;

    int cnt = 0;
    while (cnt < POST_NMS) {
        int c = 0x7fffffff;
        if (v0) c = (w0 << 6) + __builtin_ctzll(v0);
        else if (v1) c = (w1 << 6) + __builtin_ctzll(v1);
        unsigned long long bal = __ballot((v0 | v1) != 0ULL);
        if (!bal) break;
        int F = __builtin_ctzll(bal);
        int g = __shfl(c, F, 64);
        const int wg = g >> 6, bg = g & 63;

        if (t == 0) {
            float4 bb = sboxes[g];
            *(float4*)(prop + cnt * 4) = bb;
        }
        const unsigned long long* row = mask + (size_t)g * NWORDS;
        unsigned long long m0 = (w0 >= wg) ? row[w0] : 0ULL;
        unsigned long long m1 = (w1 >= wg) ? row[w1] : 0ULL;
        v0 &= ~m0; v1 &= ~m1;
        if (w0 == wg) v0 &= ~(1ULL << bg);
        if (w1 == wg) v1 &= ~(1ULL << bg);
        ++cnt;
    }
}

// =====================================================================
extern "C" void kernel_launch(void* const* d_in, const int* in_sizes, int n_in,
                              void* d_out, int out_size, void* d_ws, size_t ws_size,
                              hipStream_t stream)
{
    const float*  feats   = (const float*)d_in[0];
    const float4* ancs    = (const float4*)d_in[1];
    // d_in[2] = ancs_valid (unused by reference)
    const float*  w_bneck = (const float*)d_in[3];
    const float*  b_bneck = (const float*)d_in[4];
    const float*  w_cls   = (const float*)d_in[5];
    const float*  b_cls   = (const float*)d_in[6];
    const float*  w_reg   = (const float*)d_in[7];
    const float*  b_reg   = (const float*)d_in[8];

    float* out = (float*)d_out;
    char*  ws  = (char*)d_ws;
    float*              h      = (float*)(ws + WS_H);
    float*              logits = (float*)(ws + WS_LOGITS);
    float4*             boxes  = (float4*)(ws + WS_BOXES);
    unsigned int*       histN  = (unsigned int*)(ws + WS_HISTN); // aliases h
    unsigned int*       hist   = (unsigned int*)(ws + WS_HIST);
    float*              wcomb  = (float*)(ws + WS_WCOMB);        // aliases hist
    unsigned int*       meta   = (unsigned int*)(ws + WS_META);
    unsigned long long* coll   = (unsigned long long*)(ws + WS_COLL);
    float4*             sboxes = (float4*)(ws + WS_SBOX);
    unsigned long long* mask   = (unsigned long long*)(ws + WS_MASK); // aliases h

    hipMemsetAsync(ws + WS_META, 0, 256, stream);

    wprep_kernel<<<96, 256, 0, stream>>>(w_cls, w_reg, wcomb);
    gemm1_kernel<<<dim3(128, 4), 256, 0, stream>>>(feats, w_bneck, b_bneck, h);
    gemm2_kernel<<<256, 256, 0, stream>>>(h, wcomb, b_cls, b_reg, logits);
    // histN region (aliases h) becomes dead only after gemm2 completes
    hipMemsetAsync(ws + WS_HISTN, 0, (size_t)NHCOPY * 65536 * 4, stream);
    decode_kernel<<<576, 256, 0, stream>>>(logits, ancs, out, boxes, histN);
    hreduce_kernel<<<256, 256, 0, stream>>>(histN, hist);
    scan_kernel<<<1, 256, 0, stream>>>(hist, meta);
    collect_kernel<<<576, 256, 0, stream>>>(out, meta, coll, &meta[0]);
    rank_kernel<<<32, 256, 0, stream>>>(coll, meta, boxes, sboxes);
    nmsmat_kernel<<<dim3(94, 94), 64, 0, stream>>>(sboxes, mask);
    nmsresolve_kernel<<<1, 64, 0, stream>>>(sboxes, mask, out + PROP_OFF);
}